// Round 1
// baseline (2238.605 us; speedup 1.0000x reference)
//
#include <hip/hip_runtime.h>
#include <hip/hip_bf16.h>
#include <stdint.h>

#define HD 4096
#define VD 32000
#define BT 2048        // B*T rows
#define TT 512
#define M_TILE 256
#define N_TILE 64
#define BK 64
#define KSTEPS (HD / BK)       // 64
#define NCHUNK (VD / N_TILE)   // 500
#define MBLK (BT / M_TILE)     // 8
#define IGNORE_IDX (-100)

typedef __attribute__((ext_vector_type(8))) short short8;
typedef __attribute__((ext_vector_type(4))) float f32x4;

__device__ __forceinline__ uint16_t f2bf(float f) {
    uint32_t u = __float_as_uint(f);
    u += 0x7FFFu + ((u >> 16) & 1u);   // round-to-nearest-even
    return (uint16_t)(u >> 16);
}

// ---------------- kernel 0: convert both inputs f32 -> bf16 ----------------
__global__ void convert_x(const float* __restrict__ x0, const float* __restrict__ x1,
                          uint16_t* __restrict__ xbf) {
    const int64_t n4 = (int64_t)BT * HD / 4;
    ushort4* o0 = (ushort4*)xbf;
    ushort4* o1 = (ushort4*)(xbf + (int64_t)BT * HD);
    for (int64_t i = blockIdx.x * (int64_t)blockDim.x + threadIdx.x; i < n4;
         i += (int64_t)gridDim.x * blockDim.x) {
        float4 a = ((const float4*)x0)[i];
        float4 b = ((const float4*)x1)[i];
        ushort4 ua, ub;
        ua.x = f2bf(a.x); ua.y = f2bf(a.y); ua.z = f2bf(a.z); ua.w = f2bf(a.w);
        ub.x = f2bf(b.x); ub.y = f2bf(b.y); ub.z = f2bf(b.z); ub.w = f2bf(b.w);
        o0[i] = ua;
        o1[i] = ub;
    }
}

// ---------------- kernel 1: fused GEMM + chunk-local LSE partials ----------------
// grid: (NCHUNK, MBLK, 2 models), block: 256 (4 waves, each wave = 64 rows x 64 cols)
__global__ __launch_bounds__(256) void gemm_lse(
    const uint16_t* __restrict__ xbf,
    const float* __restrict__ w0, const float* __restrict__ b0,
    const float* __restrict__ w1, const float* __restrict__ b1,
    const int* __restrict__ target,
    float* __restrict__ partials, float* __restrict__ tgtlog)
{
    const int chunk = blockIdx.x;   // 0..499
    const int mb    = blockIdx.y;   // 0..7
    const int model = blockIdx.z;   // 0..1
    const float* w    = model ? w1 : w0;
    const float* bias = model ? b1 : b0;
    const uint16_t* xb = xbf + (size_t)model * BT * HD;

    const int row0 = mb * M_TILE;
    const int c0   = chunk * N_TILE;

    const int tid  = threadIdx.x;
    const int lane = tid & 63;
    const int wid  = tid >> 6;       // 0..3 = M-wave

    // LDS tiles: row-major [row][BK] bf16 (128B rows), 16B chunks XOR-swizzled by (row&7)<<4
    __shared__ uint16_t As[M_TILE * BK];   // 32 KB
    __shared__ uint16_t Bs[N_TILE * BK];   // 8 KB

    f32x4 acc[4][4];
#pragma unroll
    for (int i = 0; i < 4; ++i)
#pragma unroll
        for (int j = 0; j < 4; ++j) acc[i][j] = (f32x4){0.f, 0.f, 0.f, 0.f};

    // staging: each thread owns one 16B slot (8 elems) of a row; 32 rows per round
    const int ss   = tid & 7;        // k-slot within row
    const int srow = tid >> 3;       // 0..31
    const int swz_w = (srow & 7) << 4;

    // fragment read addressing
    const int lane15 = lane & 15;
    const int kg     = lane >> 4;    // 0..3
    const int swz_r  = (lane & 7) << 4;

    const uint16_t* aptr = xb + (size_t)(row0 + srow) * HD + ss * 8;
    const float*    bptr = w  + (size_t)(c0   + srow) * HD + ss * 8;

    for (int kt = 0; kt < KSTEPS; ++kt) {
        const int kofs = kt * BK;
        uint4  av[8];
        float4 bv[2][2];
#pragma unroll
        for (int r = 0; r < 8; ++r)
            av[r] = *(const uint4*)(aptr + (size_t)r * 32 * HD + kofs);
#pragma unroll
        for (int r = 0; r < 2; ++r) {
            const float* p = bptr + (size_t)r * 32 * HD + kofs;
            bv[r][0] = *(const float4*)(p);
            bv[r][1] = *(const float4*)(p + 4);
        }
#pragma unroll
        for (int r = 0; r < 8; ++r) {
            const int row_l = srow + r * 32;
            const int off = (row_l * 128 + ss * 16) ^ swz_w;
            *(uint4*)((char*)As + off) = av[r];
        }
#pragma unroll
        for (int r = 0; r < 2; ++r) {
            const int row_l = srow + r * 32;
            float fv[8] = {bv[r][0].x, bv[r][0].y, bv[r][0].z, bv[r][0].w,
                           bv[r][1].x, bv[r][1].y, bv[r][1].z, bv[r][1].w};
            uint32_t pk[4];
#pragma unroll
            for (int e = 0; e < 4; ++e)
                pk[e] = (uint32_t)f2bf(fv[2 * e]) | ((uint32_t)f2bf(fv[2 * e + 1]) << 16);
            const int off = (row_l * 128 + ss * 16) ^ swz_w;
            *(uint4*)((char*)Bs + off) = *(uint4*)pk;
        }
        __syncthreads();
#pragma unroll
        for (int ks = 0; ks < 2; ++ks) {
            short8 af[4], bf[4];
#pragma unroll
            for (int mi = 0; mi < 4; ++mi) {
                const int arow = wid * 64 + mi * 16 + lane15;
                const int off = (arow * 128 + ks * 64 + kg * 16) ^ swz_r;
                af[mi] = *(const short8*)((const char*)As + off);
            }
#pragma unroll
            for (int ni = 0; ni < 4; ++ni) {
                const int brow = ni * 16 + lane15;
                const int off = (brow * 128 + ks * 64 + kg * 16) ^ swz_r;
                bf[ni] = *(const short8*)((const char*)Bs + off);
            }
#pragma unroll
            for (int mi = 0; mi < 4; ++mi)
#pragma unroll
                for (int ni = 0; ni < 4; ++ni)
                    acc[mi][ni] = __builtin_amdgcn_mfma_f32_16x16x32_bf16(
                        af[mi], bf[ni], acc[mi][ni], 0, 0, 0);
        }
        __syncthreads();
    }

    // epilogue: bias add, per-row max/sumexp over this 64-col chunk, target capture
    float bv4[4];
#pragma unroll
    for (int ni = 0; ni < 4; ++ni) bv4[ni] = bias[c0 + ni * 16 + lane15];

#pragma unroll
    for (int mi = 0; mi < 4; ++mi) {
        const int grow_base = row0 + wid * 64 + mi * 16 + kg * 4;
#pragma unroll
        for (int j = 0; j < 4; ++j) {
            const int grow = grow_base + j;
            float v[4];
#pragma unroll
            for (int ni = 0; ni < 4; ++ni) v[ni] = acc[mi][ni][j] + bv4[ni];
            float m = fmaxf(fmaxf(v[0], v[1]), fmaxf(v[2], v[3]));
#pragma unroll
            for (int msk = 1; msk < 16; msk <<= 1)
                m = fmaxf(m, __shfl_xor(m, msk));
            float s = __expf(v[0] - m) + __expf(v[1] - m) +
                      __expf(v[2] - m) + __expf(v[3] - m);
#pragma unroll
            for (int msk = 1; msk < 16; msk <<= 1)
                s += __shfl_xor(s, msk);
            const int tg = target[grow];
#pragma unroll
            for (int ni = 0; ni < 4; ++ni) {
                const int gcol = c0 + ni * 16 + lane15;
                if (tg == gcol) tgtlog[model * BT + grow] = v[ni];
            }
            if (lane15 == 0) {
                const size_t po = ((size_t)(model * BT + grow) * NCHUNK + chunk) * 2;
                partials[po]     = m;
                partials[po + 1] = s;
            }
        }
    }
}

// ---------------- kernel 2: combine chunk partials -> lse -> per-token logp ----------------
// one wave per (model,row); block=256 -> 4 waves
__global__ void lse_reduce(const float* __restrict__ partials,
                           const float* __restrict__ tgtlog,
                           float* __restrict__ logp) {
    const int gw = blockIdx.x * (blockDim.x >> 6) + (threadIdx.x >> 6);
    if (gw >= 2 * BT) return;
    const int lane = threadIdx.x & 63;
    const float* p = partials + (size_t)gw * NCHUNK * 2;

    float m = -1e30f;
#pragma unroll
    for (int i = 0; i < 8; ++i) {
        const int c = lane + i * 64;
        if (c < NCHUNK) m = fmaxf(m, p[c * 2]);
    }
#pragma unroll
    for (int msk = 1; msk < 64; msk <<= 1) m = fmaxf(m, __shfl_xor(m, msk));
    float s = 0.f;
#pragma unroll
    for (int i = 0; i < 8; ++i) {
        const int c = lane + i * 64;
        if (c < NCHUNK) s += p[c * 2 + 1] * __expf(p[c * 2] - m);
    }
#pragma unroll
    for (int msk = 1; msk < 64; msk <<= 1) s += __shfl_xor(s, msk);
    if (lane == 0) {
        const float lse = m + __logf(s);
        logp[gw] = tgtlog[gw] - lse;
    }
}

// ---------------- kernel 3: KTO loss ----------------
__global__ void final_loss(const float* __restrict__ logp, const int* __restrict__ target,
                           const int* __restrict__ pref, const float* __restrict__ kl,
                           float* __restrict__ out) {
    const int t = threadIdx.x;          // 512 threads
    const int lane = t & 63, wv = t >> 6;
    __shared__ float rp[4][8], rr[4][8], rm[4][8];
#pragma unroll
    for (int b = 0; b < 4; ++b) {
        const int idx = b * TT + t;
        const int tg = target[idx];
        const bool mk = (tg != IGNORE_IDX);
        float lp = mk ? logp[idx] : 0.f;
        float lr = mk ? logp[BT + idx] : 0.f;
        float mc = mk ? 1.f : 0.f;
        for (int off = 32; off; off >>= 1) {
            lp += __shfl_down(lp, off);
            lr += __shfl_down(lr, off);
            mc += __shfl_down(mc, off);
        }
        if (lane == 0) { rp[b][wv] = lp; rr[b][wv] = lr; rm[b][wv] = mc; }
    }
    __syncthreads();
    if (t == 0) {
        float loss = 0.f;
        for (int b = 0; b < 4; ++b) {
            float sp = 0.f, sr = 0.f, sm = 0.f;
            for (int i = 0; i < 8; ++i) { sp += rp[b][i]; sr += rr[b][i]; sm += rm[b][i]; }
            const float denom = fmaxf(sm, 1.f);
            const float lrb = (sp - sr) / denom;
            const float mult = pref[b] ? 1.f : -1.f;
            const float z = 0.1f * (lrb - kl[0]) * mult;
            loss += 1.f / (1.f + __expf(z));   // 1 - sigmoid(z)
        }
        out[0] = loss * 0.25f;
    }
}

extern "C" void kernel_launch(void* const* d_in, const int* in_sizes, int n_in,
                              void* d_out, int out_size, void* d_ws, size_t ws_size,
                              hipStream_t stream) {
    const float* x    = (const float*)d_in[0];
    const float* w0   = (const float*)d_in[1];
    const float* b0   = (const float*)d_in[2];
    const int*   tgt  = (const int*)d_in[3];
    const int*   pref = (const int*)d_in[4];
    const float* xr   = (const float*)d_in[5];
    const float* w1   = (const float*)d_in[6];
    const float* b1   = (const float*)d_in[7];
    const float* kl   = (const float*)d_in[8];
    float* out = (float*)d_out;

    // ws layout: xbf [2][BT][HD] bf16 | partials [2*BT][NCHUNK][2] f32 | tgtlog [2*BT] | logp [2*BT]
    uint16_t* xbf     = (uint16_t*)d_ws;
    float*    partials = (float*)((char*)d_ws + (size_t)2 * BT * HD * 2);
    float*    tgtlog   = partials + (size_t)2 * BT * NCHUNK * 2;
    float*    logp     = tgtlog + 2 * BT;

    hipLaunchKernelGGL(convert_x, dim3(1024), dim3(256), 0, stream, x, xr, xbf);
    hipLaunchKernelGGL(gemm_lse, dim3(NCHUNK, MBLK, 2), dim3(256), 0, stream,
                       xbf, w0, b0, w1, b1, tgt, partials, tgtlog);
    hipLaunchKernelGGL(lse_reduce, dim3(2 * BT / 4), dim3(256), 0, stream,
                       partials, tgtlog, logp);
    hipLaunchKernelGGL(final_loss, dim3(1), dim3(512), 0, stream, logp, tgt, pref, kl, out);
}

// Round 2
// 1867.011 us; speedup vs baseline: 1.1990x; 1.1990x over previous
//
#include <hip/hip_runtime.h>
#include <hip/hip_bf16.h>
#include <stdint.h>

#define HD 4096
#define VD 32000
#define BT 2048        // B*T rows
#define TT 512
#define M_TILE 256
#define N_TILE 64
#define BK 64
#define KSTEPS (HD / BK)       // 64
#define NCHUNK (VD / N_TILE)   // 500
#define MBLK (BT / M_TILE)     // 8
#define NWG (MBLK * NCHUNK * 2) // 8000
#define IGNORE_IDX (-100)

typedef __attribute__((ext_vector_type(8))) short short8;
typedef __attribute__((ext_vector_type(4))) float f32x4;

__device__ __forceinline__ uint16_t f2bf(float f) {
    uint32_t u = __float_as_uint(f);
    u += 0x7FFFu + ((u >> 16) & 1u);   // round-to-nearest-even
    return (uint16_t)(u >> 16);
}

__device__ __forceinline__ void gload16(const void* g, void* l) {
    __builtin_amdgcn_global_load_lds(
        (const __attribute__((address_space(1))) void*)g,
        (__attribute__((address_space(3))) void*)l, 16, 0, 0);
}

// ---------------- kernel 0a: convert x inputs f32 -> bf16 ----------------
__global__ void convert_x(const float* __restrict__ x0, const float* __restrict__ x1,
                          uint16_t* __restrict__ xbf) {
    const int64_t n4 = (int64_t)BT * HD / 4;
    ushort4* o0 = (ushort4*)xbf;
    ushort4* o1 = (ushort4*)(xbf + (int64_t)BT * HD);
    for (int64_t i = blockIdx.x * (int64_t)blockDim.x + threadIdx.x; i < n4;
         i += (int64_t)gridDim.x * blockDim.x) {
        float4 a = ((const float4*)x0)[i];
        float4 b = ((const float4*)x1)[i];
        ushort4 ua, ub;
        ua.x = f2bf(a.x); ua.y = f2bf(a.y); ua.z = f2bf(a.z); ua.w = f2bf(a.w);
        ub.x = f2bf(b.x); ub.y = f2bf(b.y); ub.z = f2bf(b.z); ub.w = f2bf(b.w);
        o0[i] = ua;
        o1[i] = ub;
    }
}

// ---------------- kernel 0b: convert weights f32 -> bf16 ----------------
__global__ void convert_w(const float* __restrict__ w0, const float* __restrict__ w1,
                          uint16_t* __restrict__ wbf) {
    const int64_t n4 = (int64_t)VD * HD / 4;
    ushort4* o0 = (ushort4*)wbf;
    ushort4* o1 = (ushort4*)(wbf + (int64_t)VD * HD);
    for (int64_t i = blockIdx.x * (int64_t)blockDim.x + threadIdx.x; i < n4;
         i += (int64_t)gridDim.x * blockDim.x) {
        float4 a = ((const float4*)w0)[i];
        float4 b = ((const float4*)w1)[i];
        ushort4 ua, ub;
        ua.x = f2bf(a.x); ua.y = f2bf(a.y); ua.z = f2bf(a.z); ua.w = f2bf(a.w);
        ub.x = f2bf(b.x); ub.y = f2bf(b.y); ub.z = f2bf(b.z); ub.w = f2bf(b.w);
        o0[i] = ua;
        o1[i] = ub;
    }
}

// ---------------- kernel 1: fused GEMM + chunk-local LSE partials ----------------
// 1D grid NWG, bijective XCD swizzle, mb-fastest decomposition so 8 consecutive
// blocks (same XCD) share one 0.5MB weight tile in L2.
// block: 256 (4 waves, each wave = 64 rows x 64 cols of the 256x64 tile)
template<bool WBF>
__global__ __launch_bounds__(256) void gemm_lse(
    const uint16_t* __restrict__ xbf,
    const void* __restrict__ w0v, const float* __restrict__ b0,
    const void* __restrict__ w1v, const float* __restrict__ b1,
    const int* __restrict__ target,
    float* __restrict__ partials, float* __restrict__ tgtlog)
{
    // XCD swizzle: NWG % 8 == 0 -> simple bijective form
    const int orig = blockIdx.x;
    const int wgid = (orig & 7) * (NWG / 8) + (orig >> 3);
    const int mb    = wgid & 7;            // fastest: 8 blocks share a weight tile
    const int rest  = wgid >> 3;
    const int chunk = rest % NCHUNK;
    const int model = rest / NCHUNK;

    const float* bias = model ? b1 : b0;
    const uint16_t* xb = xbf + (size_t)model * BT * HD;

    const int row0 = mb * M_TILE;
    const int c0   = chunk * N_TILE;

    const int tid  = threadIdx.x;
    const int lane = tid & 63;
    const int wid  = tid >> 6;

    // LDS: row-major [row][BK] bf16 (128B rows); 16B slots XOR-swizzled by (row&7)<<4.
    // global_load_lds writes LINEAR dest; source address is pre-swizzled (m173/rule 21).
    __shared__ uint16_t As[M_TILE * BK];   // 32 KB
    __shared__ uint16_t Bs[N_TILE * BK];   // 8 KB

    f32x4 acc[4][4];
#pragma unroll
    for (int i = 0; i < 4; ++i)
#pragma unroll
        for (int j = 0; j < 4; ++j) acc[i][j] = (f32x4){0.f, 0.f, 0.f, 0.f};

    // gload addressing: per 1KB chunk, lane l -> row = 8*chunkrow + l/8, stored slot l&7,
    // source slot = (l&7) ^ (row&7) = (l&7) ^ (l>>3)
    const int srow8 = lane >> 3;               // 0..7
    const int slot  = (lane & 7) ^ srow8;      // pre-swizzled source slot
    const uint16_t* agsrc = xb + (size_t)(row0 + wid * 64 + srow8) * HD + slot * 8;
    char* aldst = (char*)As + wid * 8192;

    const uint16_t* bgsrc_bf = nullptr;
    const float* w_f32 = nullptr;
    if constexpr (WBF) {
        const uint16_t* wb = (const uint16_t*)(model ? w1v : w0v);
        bgsrc_bf = wb + (size_t)(c0 + wid * 16 + srow8) * HD + slot * 8;
    } else {
        w_f32 = (const float*)(model ? w1v : w0v);
    }
    char* bldst = (char*)Bs + wid * 2048;

    // fallback reg-staging addressing (f32 weights)
    const int ss   = tid & 7;
    const int srow = tid >> 3;
    const int swz_w = (srow & 7) << 4;
    const float* bptr = WBF ? nullptr : (w_f32 + (size_t)(c0 + srow) * HD + ss * 8);

    // fragment read addressing
    const int lane15 = lane & 15;
    const int kg     = lane >> 4;
    const int swz_r  = (lane & 7) << 4;

    for (int kt = 0; kt < KSTEPS; ++kt) {
        const int kofs = kt * BK;
        // A: 8 chunks x 1KB per wave -> 32KB
#pragma unroll
        for (int c = 0; c < 8; ++c)
            gload16(agsrc + (size_t)c * 8 * HD + kofs, aldst + c * 1024);
        if constexpr (WBF) {
            // B: 2 chunks x 1KB per wave -> 8KB
#pragma unroll
            for (int c = 0; c < 2; ++c)
                gload16(bgsrc_bf + (size_t)c * 8 * HD + kofs, bldst + c * 1024);
        } else {
            float4 bv[2][2];
#pragma unroll
            for (int r = 0; r < 2; ++r) {
                const float* p = bptr + (size_t)r * 32 * HD + kofs;
                bv[r][0] = *(const float4*)(p);
                bv[r][1] = *(const float4*)(p + 4);
            }
#pragma unroll
            for (int r = 0; r < 2; ++r) {
                const int row_l = srow + r * 32;
                float fv[8] = {bv[r][0].x, bv[r][0].y, bv[r][0].z, bv[r][0].w,
                               bv[r][1].x, bv[r][1].y, bv[r][1].z, bv[r][1].w};
                uint32_t pk[4];
#pragma unroll
                for (int e = 0; e < 4; ++e)
                    pk[e] = (uint32_t)f2bf(fv[2 * e]) | ((uint32_t)f2bf(fv[2 * e + 1]) << 16);
                const int off = (row_l * 128 + ss * 16) ^ swz_w;
                *(uint4*)((char*)Bs + off) = *(uint4*)pk;
            }
        }
        __syncthreads();
#pragma unroll
        for (int ks = 0; ks < 2; ++ks) {
            short8 af[4], bf[4];
#pragma unroll
            for (int mi = 0; mi < 4; ++mi) {
                const int arow = wid * 64 + mi * 16 + lane15;
                const int off = (arow * 128 + ks * 64 + kg * 16) ^ swz_r;
                af[mi] = *(const short8*)((const char*)As + off);
            }
#pragma unroll
            for (int ni = 0; ni < 4; ++ni) {
                const int brow = ni * 16 + lane15;
                const int off = (brow * 128 + ks * 64 + kg * 16) ^ swz_r;
                bf[ni] = *(const short8*)((const char*)Bs + off);
            }
#pragma unroll
            for (int mi = 0; mi < 4; ++mi)
#pragma unroll
                for (int ni = 0; ni < 4; ++ni)
                    acc[mi][ni] = __builtin_amdgcn_mfma_f32_16x16x32_bf16(
                        af[mi], bf[ni], acc[mi][ni], 0, 0, 0);
        }
        __syncthreads();
    }

    // epilogue: bias add, per-row max/sumexp over this 64-col chunk, target capture
    float bv4[4];
#pragma unroll
    for (int ni = 0; ni < 4; ++ni) bv4[ni] = bias[c0 + ni * 16 + lane15];

#pragma unroll
    for (int mi = 0; mi < 4; ++mi) {
        const int grow_base = row0 + wid * 64 + mi * 16 + kg * 4;
#pragma unroll
        for (int j = 0; j < 4; ++j) {
            const int grow = grow_base + j;
            float v[4];
#pragma unroll
            for (int ni = 0; ni < 4; ++ni) v[ni] = acc[mi][ni][j] + bv4[ni];
            float m = fmaxf(fmaxf(v[0], v[1]), fmaxf(v[2], v[3]));
#pragma unroll
            for (int msk = 1; msk < 16; msk <<= 1)
                m = fmaxf(m, __shfl_xor(m, msk));
            float s = __expf(v[0] - m) + __expf(v[1] - m) +
                      __expf(v[2] - m) + __expf(v[3] - m);
#pragma unroll
            for (int msk = 1; msk < 16; msk <<= 1)
                s += __shfl_xor(s, msk);
            const int tg = target[grow];
#pragma unroll
            for (int ni = 0; ni < 4; ++ni) {
                const int gcol = c0 + ni * 16 + lane15;
                if (tg == gcol) tgtlog[model * BT + grow] = v[ni];
            }
            if (lane15 == 0) {
                const size_t po = ((size_t)(model * BT + grow) * NCHUNK + chunk) * 2;
                partials[po]     = m;
                partials[po + 1] = s;
            }
        }
    }
}

// ---------------- kernel 2: combine chunk partials -> lse -> per-token logp ----------------
__global__ void lse_reduce(const float* __restrict__ partials,
                           const float* __restrict__ tgtlog,
                           float* __restrict__ logp) {
    const int gw = blockIdx.x * (blockDim.x >> 6) + (threadIdx.x >> 6);
    if (gw >= 2 * BT) return;
    const int lane = threadIdx.x & 63;
    const float* p = partials + (size_t)gw * NCHUNK * 2;

    float m = -1e30f;
#pragma unroll
    for (int i = 0; i < 8; ++i) {
        const int c = lane + i * 64;
        if (c < NCHUNK) m = fmaxf(m, p[c * 2]);
    }
#pragma unroll
    for (int msk = 1; msk < 64; msk <<= 1) m = fmaxf(m, __shfl_xor(m, msk));
    float s = 0.f;
#pragma unroll
    for (int i = 0; i < 8; ++i) {
        const int c = lane + i * 64;
        if (c < NCHUNK) s += p[c * 2 + 1] * __expf(p[c * 2] - m);
    }
#pragma unroll
    for (int msk = 1; msk < 64; msk <<= 1) s += __shfl_xor(s, msk);
    if (lane == 0) {
        const float lse = m + __logf(s);
        logp[gw] = tgtlog[gw] - lse;
    }
}

// ---------------- kernel 3: KTO loss ----------------
__global__ void final_loss(const float* __restrict__ logp, const int* __restrict__ target,
                           const int* __restrict__ pref, const float* __restrict__ kl,
                           float* __restrict__ out) {
    const int t = threadIdx.x;          // 512 threads
    const int lane = t & 63, wv = t >> 6;
    __shared__ float rp[4][8], rr[4][8], rm[4][8];
#pragma unroll
    for (int b = 0; b < 4; ++b) {
        const int idx = b * TT + t;
        const int tg = target[idx];
        const bool mk = (tg != IGNORE_IDX);
        float lp = mk ? logp[idx] : 0.f;
        float lr = mk ? logp[BT + idx] : 0.f;
        float mc = mk ? 1.f : 0.f;
        for (int off = 32; off; off >>= 1) {
            lp += __shfl_down(lp, off);
            lr += __shfl_down(lr, off);
            mc += __shfl_down(mc, off);
        }
        if (lane == 0) { rp[b][wv] = lp; rr[b][wv] = lr; rm[b][wv] = mc; }
    }
    __syncthreads();
    if (t == 0) {
        float loss = 0.f;
        for (int b = 0; b < 4; ++b) {
            float sp = 0.f, sr = 0.f, sm = 0.f;
            for (int i = 0; i < 8; ++i) { sp += rp[b][i]; sr += rr[b][i]; sm += rm[b][i]; }
            const float denom = fmaxf(sm, 1.f);
            const float lrb = (sp - sr) / denom;
            const float mult = pref[b] ? 1.f : -1.f;
            const float z = 0.1f * (lrb - kl[0]) * mult;
            loss += 1.f / (1.f + __expf(z));   // 1 - sigmoid(z)
        }
        out[0] = loss * 0.25f;
    }
}

extern "C" void kernel_launch(void* const* d_in, const int* in_sizes, int n_in,
                              void* d_out, int out_size, void* d_ws, size_t ws_size,
                              hipStream_t stream) {
    const float* x    = (const float*)d_in[0];
    const float* w0   = (const float*)d_in[1];
    const float* b0   = (const float*)d_in[2];
    const int*   tgt  = (const int*)d_in[3];
    const int*   pref = (const int*)d_in[4];
    const float* xr   = (const float*)d_in[5];
    const float* w1   = (const float*)d_in[6];
    const float* b1   = (const float*)d_in[7];
    const float* kl   = (const float*)d_in[8];
    float* out = (float*)d_out;

    // ws layout: xbf | partials | tgtlog | logp | [wbf if it fits]
    const size_t xbf_b  = (size_t)2 * BT * HD * 2;          // 33.55 MB
    const size_t part_b = (size_t)2 * BT * NCHUNK * 2 * 4;  // 16.38 MB
    const size_t tl_b   = (size_t)2 * BT * 4;
    const size_t wbf_b  = (size_t)2 * VD * HD * 2;          // 524.3 MB

    char* wp = (char*)d_ws;
    uint16_t* xbf     = (uint16_t*)wp;                 wp += xbf_b;
    float*    partials = (float*)wp;                   wp += part_b;
    float*    tgtlog   = (float*)wp;                   wp += tl_b;
    float*    logp     = (float*)wp;                   wp += tl_b;
    uint16_t* wbf      = (uint16_t*)wp;
    const bool use_wbf = ws_size >= (xbf_b + part_b + 2 * tl_b + wbf_b);

    hipLaunchKernelGGL(convert_x, dim3(1024), dim3(256), 0, stream, x, xr, xbf);
    if (use_wbf) {
        hipLaunchKernelGGL(convert_w, dim3(4096), dim3(256), 0, stream, w0, w1, wbf);
        hipLaunchKernelGGL(gemm_lse<true>, dim3(NWG), dim3(256), 0, stream,
                           xbf, wbf, b0, wbf + (size_t)VD * HD, b1, tgt, partials, tgtlog);
    } else {
        hipLaunchKernelGGL(gemm_lse<false>, dim3(NWG), dim3(256), 0, stream,
                           xbf, w0, b0, w1, b1, tgt, partials, tgtlog);
    }
    hipLaunchKernelGGL(lse_reduce, dim3(2 * BT / 4), dim3(256), 0, stream,
                       partials, tgtlog, logp);
    hipLaunchKernelGGL(final_loss, dim3(1), dim3(512), 0, stream, logp, tgt, pref, kl, out);
}

// Round 3
// 1770.926 us; speedup vs baseline: 1.2641x; 1.0543x over previous
//
#include <hip/hip_runtime.h>
#include <hip/hip_bf16.h>
#include <stdint.h>

#define HD 4096
#define VD 32000
#define BT 2048        // B*T rows
#define TT 512
#define IGNORE_IDX (-100)

// bf16 8-wave main GEMM geometry
#define BM 256
#define BN 256
#define BKT 64
#define KT (HD / BKT)          // 64 K-tiles
#define NB (VD / BN)           // 125
#define MB (BT / BM)           // 8
#define NWG2 (MB * NB * 2)     // 2000

// partials granularity (64 columns per chunk) — shared with f32 fallback
#define NCHUNK (VD / 64)       // 500

typedef __attribute__((ext_vector_type(8))) short short8;
typedef __attribute__((ext_vector_type(4))) float f32x4;

__device__ __forceinline__ uint16_t f2bf(float f) {
    uint32_t u = __float_as_uint(f);
    u += 0x7FFFu + ((u >> 16) & 1u);   // round-to-nearest-even
    return (uint16_t)(u >> 16);
}

__device__ __forceinline__ void gload16(const void* g, void* l) {
    __builtin_amdgcn_global_load_lds(
        (const __attribute__((address_space(1))) void*)g,
        (__attribute__((address_space(3))) void*)l, 16, 0, 0);
}

// ---------------- kernel 0a: convert x inputs f32 -> bf16 ----------------
__global__ void convert_x(const float* __restrict__ x0, const float* __restrict__ x1,
                          uint16_t* __restrict__ xbf) {
    const int64_t n4 = (int64_t)BT * HD / 4;
    ushort4* o0 = (ushort4*)xbf;
    ushort4* o1 = (ushort4*)(xbf + (int64_t)BT * HD);
    for (int64_t i = blockIdx.x * (int64_t)blockDim.x + threadIdx.x; i < n4;
         i += (int64_t)gridDim.x * blockDim.x) {
        float4 a = ((const float4*)x0)[i];
        float4 b = ((const float4*)x1)[i];
        ushort4 ua, ub;
        ua.x = f2bf(a.x); ua.y = f2bf(a.y); ua.z = f2bf(a.z); ua.w = f2bf(a.w);
        ub.x = f2bf(b.x); ub.y = f2bf(b.y); ub.z = f2bf(b.z); ub.w = f2bf(b.w);
        o0[i] = ua;
        o1[i] = ub;
    }
}

// ---------------- kernel 0b: convert weights f32 -> bf16 ----------------
__global__ void convert_w(const float* __restrict__ w0, const float* __restrict__ w1,
                          uint16_t* __restrict__ wbf) {
    const int64_t n4 = (int64_t)VD * HD / 4;
    ushort4* o0 = (ushort4*)wbf;
    ushort4* o1 = (ushort4*)(wbf + (int64_t)VD * HD);
    for (int64_t i = blockIdx.x * (int64_t)blockDim.x + threadIdx.x; i < n4;
         i += (int64_t)gridDim.x * blockDim.x) {
        float4 a = ((const float4*)w0)[i];
        float4 b = ((const float4*)w1)[i];
        ushort4 ua, ub;
        ua.x = f2bf(a.x); ua.y = f2bf(a.y); ua.z = f2bf(a.z); ua.w = f2bf(a.w);
        ub.x = f2bf(b.x); ub.y = f2bf(b.y); ub.z = f2bf(b.z); ub.w = f2bf(b.w);
        o0[i] = ua;
        o1[i] = ub;
    }
}

// ---------------- kernel 1 (main): 256x256 counted-vmcnt GEMM + LSE partials ----------------
// 8 waves (2M x 4N), per-wave 128x64 output. LDS: 2 x (A 32KB + B 32KB) = 128KB.
// Per K-tile: issue order B(t+1) then A(t+1); waits are vmcnt(4) (exactly 8
// outstanding at each wait; oldest 4 = the operand needed after the barrier).
__global__ __launch_bounds__(512, 2) void gemm_lse_bf(
    const uint16_t* __restrict__ xbf, const uint16_t* __restrict__ wbf,
    const float* __restrict__ b0, const float* __restrict__ b1,
    const int* __restrict__ target,
    float* __restrict__ partials, float* __restrict__ tgtlog)
{
    __shared__ uint16_t As[2 * BM * BKT];  // 64 KB (2 buffers)
    __shared__ uint16_t Bs[2 * BN * BKT];  // 64 KB

    // bijective XCD swizzle (NWG2 % 8 == 0); mb fastest so same-XCD neighbors
    // share the 2MB weight panel in L2.
    const int orig = blockIdx.x;
    const int wgid = (orig & 7) * (NWG2 / 8) + (orig >> 3);
    const int mb    = wgid & 7;
    const int rest  = wgid >> 3;
    const int nb    = rest % NB;
    const int model = rest / NB;

    const uint16_t* xb = xbf + (size_t)model * BT * HD;
    const uint16_t* wb = wbf + (size_t)model * VD * HD;
    const float* bias  = model ? b1 : b0;

    const int row0 = mb * BM;
    const int c0   = nb * BN;

    const int tid    = threadIdx.x;
    const int lane   = tid & 63;
    const int wid    = tid >> 6;       // 0..7
    const int wr     = wid >> 2;       // 0..1  (M half)
    const int wc     = wid & 3;        // 0..3  (N quarter)

    const int lane15 = lane & 15;
    const int kg     = lane >> 4;
    const int swz    = (lane & 7) << 4;

    // staging: per wave 4 x 1KB chunks per matrix per tile; 8 rows per chunk.
    // LDS dest linear; global source slot pre-swizzled by (row&7) (= lane>>3).
    const int srow8 = lane >> 3;
    const int slot  = (lane & 7) ^ srow8;
    const uint16_t* agp = xb + (size_t)(row0 + wid * 32 + srow8) * HD + slot * 8;
    const uint16_t* bgp = wb + (size_t)(c0   + wid * 32 + srow8) * HD + slot * 8;

    f32x4 acc[8][4];
#pragma unroll
    for (int i = 0; i < 8; ++i)
#pragma unroll
        for (int j = 0; j < 4; ++j) acc[i][j] = (f32x4){0.f, 0.f, 0.f, 0.f};

    // prologue: stage tile 0 — B first, then A (issue order matters for vmcnt)
#pragma unroll
    for (int i = 0; i < 4; ++i)
        gload16(bgp + (size_t)i * 8 * HD, (char*)Bs + wid * 4096 + i * 1024);
#pragma unroll
    for (int i = 0; i < 4; ++i)
        gload16(agp + (size_t)i * 8 * HD, (char*)As + wid * 4096 + i * 1024);

    for (int t = 0; t < KT; ++t) {
        const int cur = t & 1;
        const int nxt = cur ^ 1;
        const int curA = cur * 32768;  // byte offset of buffer in As/Bs

        // ---- top wait: retire B(t) (oldest 4 of 8 outstanding) ----
        __builtin_amdgcn_sched_barrier(0);
        asm volatile("s_waitcnt vmcnt(4)" ::: "memory");
        __builtin_amdgcn_sched_barrier(0);
        __builtin_amdgcn_s_barrier();
        __builtin_amdgcn_sched_barrier(0);

        // issue stage B(t+1) into the other buffer (freed at this barrier)
        if (t + 1 < KT) {
            const int ko = (t + 1) * BKT;
#pragma unroll
            for (int i = 0; i < 4; ++i)
                gload16(bgp + (size_t)i * 8 * HD + ko,
                        (char*)Bs + nxt * 32768 + wid * 4096 + i * 1024);
        }

        // read all B fragments for this tile (B(t) is in LDS now)
        short8 bfr[4][2];
#pragma unroll
        for (int ni = 0; ni < 4; ++ni) {
            const int brow = wc * 64 + ni * 16 + lane15;
#pragma unroll
            for (int ks = 0; ks < 2; ++ks) {
                const int off = ((brow * 128 + ks * 64 + kg * 16) ^ swz) + curA;
                bfr[ni][ks] = *(const short8*)((const char*)Bs + off);
            }
        }

        // ---- mid wait: retire A(t) (oldest 4; B(t+1) stays in flight) ----
        __builtin_amdgcn_sched_barrier(0);
        if (t + 1 < KT) { asm volatile("s_waitcnt vmcnt(4)" ::: "memory"); }
        else           { asm volatile("s_waitcnt vmcnt(0)" ::: "memory"); }
        __builtin_amdgcn_sched_barrier(0);
        __builtin_amdgcn_s_barrier();
        __builtin_amdgcn_sched_barrier(0);

        // issue stage A(t+1)
        if (t + 1 < KT) {
            const int ko = (t + 1) * BKT;
#pragma unroll
            for (int i = 0; i < 4; ++i)
                gload16(agp + (size_t)i * 8 * HD + ko,
                        (char*)As + nxt * 32768 + wid * 4096 + i * 1024);
        }

        // MFMA phases: per mi, 2 ds_read + 8 MFMA (setprio-wrapped)
#pragma unroll
        for (int mi = 0; mi < 8; ++mi) {
            const int arow = wr * 128 + mi * 16 + lane15;
            const int off0 = ((arow * 128 + 0 * 64 + kg * 16) ^ swz) + curA;
            const int off1 = ((arow * 128 + 1 * 64 + kg * 16) ^ swz) + curA;
            const short8 af0 = *(const short8*)((const char*)As + off0);
            const short8 af1 = *(const short8*)((const char*)As + off1);
            __builtin_amdgcn_s_setprio(1);
#pragma unroll
            for (int ni = 0; ni < 4; ++ni) {
                acc[mi][ni] = __builtin_amdgcn_mfma_f32_16x16x32_bf16(
                    af0, bfr[ni][0], acc[mi][ni], 0, 0, 0);
                acc[mi][ni] = __builtin_amdgcn_mfma_f32_16x16x32_bf16(
                    af1, bfr[ni][1], acc[mi][ni], 0, 0, 0);
            }
            __builtin_amdgcn_s_setprio(0);
        }
    }

    // ---- epilogue: bias, per-row max/sumexp over this wave's 64 cols ----
    float bv4[4];
#pragma unroll
    for (int ni = 0; ni < 4; ++ni) bv4[ni] = bias[c0 + wc * 64 + ni * 16 + lane15];

#pragma unroll
    for (int mi = 0; mi < 8; ++mi) {
        const int grow_base = row0 + wr * 128 + mi * 16 + kg * 4;
#pragma unroll
        for (int j = 0; j < 4; ++j) {
            const int grow = grow_base + j;
            float v[4];
#pragma unroll
            for (int ni = 0; ni < 4; ++ni) v[ni] = acc[mi][ni][j] + bv4[ni];
            float m = fmaxf(fmaxf(v[0], v[1]), fmaxf(v[2], v[3]));
#pragma unroll
            for (int msk = 1; msk < 16; msk <<= 1)
                m = fmaxf(m, __shfl_xor(m, msk));
            float s = __expf(v[0] - m) + __expf(v[1] - m) +
                      __expf(v[2] - m) + __expf(v[3] - m);
#pragma unroll
            for (int msk = 1; msk < 16; msk <<= 1)
                s += __shfl_xor(s, msk);
            const int tg = target[grow];
#pragma unroll
            for (int ni = 0; ni < 4; ++ni) {
                const int gcol = c0 + wc * 64 + ni * 16 + lane15;
                if (tg == gcol) tgtlog[model * BT + grow] = v[ni];
            }
            if (lane15 == 0) {
                const size_t po = ((size_t)(model * BT + grow) * NCHUNK + nb * 4 + wc) * 2;
                partials[po]     = m;
                partials[po + 1] = s;
            }
        }
    }
}

// ---------------- kernel 1 (fallback, f32 weights): R1 structure ----------------
__global__ __launch_bounds__(256) void gemm_lse_f32(
    const uint16_t* __restrict__ xbf,
    const float* __restrict__ w0, const float* __restrict__ b0,
    const float* __restrict__ w1, const float* __restrict__ b1,
    const int* __restrict__ target,
    float* __restrict__ partials, float* __restrict__ tgtlog)
{
    const int orig = blockIdx.x;               // grid 8000
    const int wgid = (orig & 7) * 1000 + (orig >> 3);
    const int mb    = wgid & 7;
    const int rest  = wgid >> 3;
    const int chunk = rest % 500;
    const int model = rest / 500;

    const float* w    = model ? w1 : w0;
    const float* bias = model ? b1 : b0;
    const uint16_t* xb = xbf + (size_t)model * BT * HD;

    const int row0 = mb * 256;
    const int c0   = chunk * 64;

    const int tid  = threadIdx.x;
    const int lane = tid & 63;
    const int wid  = tid >> 6;

    __shared__ uint16_t As_[256 * 64];
    __shared__ uint16_t Bs_[64 * 64];

    f32x4 acc[4][4];
#pragma unroll
    for (int i = 0; i < 4; ++i)
#pragma unroll
        for (int j = 0; j < 4; ++j) acc[i][j] = (f32x4){0.f, 0.f, 0.f, 0.f};

    const int srow8 = lane >> 3;
    const int slot  = (lane & 7) ^ srow8;
    const uint16_t* agsrc = xb + (size_t)(row0 + wid * 64 + srow8) * HD + slot * 8;
    char* aldst = (char*)As_ + wid * 8192;

    const int ss   = tid & 7;
    const int srow = tid >> 3;
    const int swz_w = (srow & 7) << 4;
    const float* bptr = w + (size_t)(c0 + srow) * HD + ss * 8;

    const int lane15 = lane & 15;
    const int kg     = lane >> 4;
    const int swz_r  = (lane & 7) << 4;

    for (int kt = 0; kt < 64; ++kt) {
        const int kofs = kt * 64;
#pragma unroll
        for (int c = 0; c < 8; ++c)
            gload16(agsrc + (size_t)c * 8 * HD + kofs, aldst + c * 1024);
        {
            float4 bv[2][2];
#pragma unroll
            for (int r = 0; r < 2; ++r) {
                const float* p = bptr + (size_t)r * 32 * HD + kofs;
                bv[r][0] = *(const float4*)(p);
                bv[r][1] = *(const float4*)(p + 4);
            }
#pragma unroll
            for (int r = 0; r < 2; ++r) {
                const int row_l = srow + r * 32;
                float fv[8] = {bv[r][0].x, bv[r][0].y, bv[r][0].z, bv[r][0].w,
                               bv[r][1].x, bv[r][1].y, bv[r][1].z, bv[r][1].w};
                uint32_t pk[4];
#pragma unroll
                for (int e = 0; e < 4; ++e)
                    pk[e] = (uint32_t)f2bf(fv[2 * e]) | ((uint32_t)f2bf(fv[2 * e + 1]) << 16);
                const int off = (row_l * 128 + ss * 16) ^ swz_w;
                *(uint4*)((char*)Bs_ + off) = *(uint4*)pk;
            }
        }
        __syncthreads();
#pragma unroll
        for (int ks = 0; ks < 2; ++ks) {
            short8 af[4], bf[4];
#pragma unroll
            for (int mi = 0; mi < 4; ++mi) {
                const int arow = wid * 64 + mi * 16 + lane15;
                const int off = (arow * 128 + ks * 64 + kg * 16) ^ swz_r;
                af[mi] = *(const short8*)((const char*)As_ + off);
            }
#pragma unroll
            for (int ni = 0; ni < 4; ++ni) {
                const int brow = ni * 16 + lane15;
                const int off = (brow * 128 + ks * 64 + kg * 16) ^ swz_r;
                bf[ni] = *(const short8*)((const char*)Bs_ + off);
            }
#pragma unroll
            for (int mi = 0; mi < 4; ++mi)
#pragma unroll
                for (int ni = 0; ni < 4; ++ni)
                    acc[mi][ni] = __builtin_amdgcn_mfma_f32_16x16x32_bf16(
                        af[mi], bf[ni], acc[mi][ni], 0, 0, 0);
        }
        __syncthreads();
    }

    float bv4[4];
#pragma unroll
    for (int ni = 0; ni < 4; ++ni) bv4[ni] = bias[c0 + ni * 16 + lane15];

#pragma unroll
    for (int mi = 0; mi < 4; ++mi) {
        const int grow_base = row0 + wid * 64 + mi * 16 + kg * 4;
#pragma unroll
        for (int j = 0; j < 4; ++j) {
            const int grow = grow_base + j;
            float v[4];
#pragma unroll
            for (int ni = 0; ni < 4; ++ni) v[ni] = acc[mi][ni][j] + bv4[ni];
            float m = fmaxf(fmaxf(v[0], v[1]), fmaxf(v[2], v[3]));
#pragma unroll
            for (int msk = 1; msk < 16; msk <<= 1)
                m = fmaxf(m, __shfl_xor(m, msk));
            float s = __expf(v[0] - m) + __expf(v[1] - m) +
                      __expf(v[2] - m) + __expf(v[3] - m);
#pragma unroll
            for (int msk = 1; msk < 16; msk <<= 1)
                s += __shfl_xor(s, msk);
            const int tg = target[grow];
#pragma unroll
            for (int ni = 0; ni < 4; ++ni) {
                const int gcol = c0 + ni * 16 + lane15;
                if (tg == gcol) tgtlog[model * BT + grow] = v[ni];
            }
            if (lane15 == 0) {
                const size_t po = ((size_t)(model * BT + grow) * NCHUNK + chunk) * 2;
                partials[po]     = m;
                partials[po + 1] = s;
            }
        }
    }
}

// ---------------- kernel 2: combine chunk partials -> lse -> per-token logp ----------------
__global__ void lse_reduce(const float* __restrict__ partials,
                           const float* __restrict__ tgtlog,
                           float* __restrict__ logp) {
    const int gw = blockIdx.x * (blockDim.x >> 6) + (threadIdx.x >> 6);
    if (gw >= 2 * BT) return;
    const int lane = threadIdx.x & 63;
    const float* p = partials + (size_t)gw * NCHUNK * 2;

    float m = -1e30f;
#pragma unroll
    for (int i = 0; i < 8; ++i) {
        const int c = lane + i * 64;
        if (c < NCHUNK) m = fmaxf(m, p[c * 2]);
    }
#pragma unroll
    for (int msk = 1; msk < 64; msk <<= 1) m = fmaxf(m, __shfl_xor(m, msk));
    float s = 0.f;
#pragma unroll
    for (int i = 0; i < 8; ++i) {
        const int c = lane + i * 64;
        if (c < NCHUNK) s += p[c * 2 + 1] * __expf(p[c * 2] - m);
    }
#pragma unroll
    for (int msk = 1; msk < 64; msk <<= 1) s += __shfl_xor(s, msk);
    if (lane == 0) {
        const float lse = m + __logf(s);
        logp[gw] = tgtlog[gw] - lse;
    }
}

// ---------------- kernel 3: KTO loss ----------------
__global__ void final_loss(const float* __restrict__ logp, const int* __restrict__ target,
                           const int* __restrict__ pref, const float* __restrict__ kl,
                           float* __restrict__ out) {
    const int t = threadIdx.x;          // 512 threads
    const int lane = t & 63, wv = t >> 6;
    __shared__ float rp[4][8], rr[4][8], rm[4][8];
#pragma unroll
    for (int b = 0; b < 4; ++b) {
        const int idx = b * TT + t;
        const int tg = target[idx];
        const bool mk = (tg != IGNORE_IDX);
        float lp = mk ? logp[idx] : 0.f;
        float lr = mk ? logp[BT + idx] : 0.f;
        float mc = mk ? 1.f : 0.f;
        for (int off = 32; off; off >>= 1) {
            lp += __shfl_down(lp, off);
            lr += __shfl_down(lr, off);
            mc += __shfl_down(mc, off);
        }
        if (lane == 0) { rp[b][wv] = lp; rr[b][wv] = lr; rm[b][wv] = mc; }
    }
    __syncthreads();
    if (t == 0) {
        float loss = 0.f;
        for (int b = 0; b < 4; ++b) {
            float sp = 0.f, sr = 0.f, sm = 0.f;
            for (int i = 0; i < 8; ++i) { sp += rp[b][i]; sr += rr[b][i]; sm += rm[b][i]; }
            const float denom = fmaxf(sm, 1.f);
            const float lrb = (sp - sr) / denom;
            const float mult = pref[b] ? 1.f : -1.f;
            const float z = 0.1f * (lrb - kl[0]) * mult;
            loss += 1.f / (1.f + __expf(z));   // 1 - sigmoid(z)
        }
        out[0] = loss * 0.25f;
    }
}

extern "C" void kernel_launch(void* const* d_in, const int* in_sizes, int n_in,
                              void* d_out, int out_size, void* d_ws, size_t ws_size,
                              hipStream_t stream) {
    const float* x    = (const float*)d_in[0];
    const float* w0   = (const float*)d_in[1];
    const float* b0   = (const float*)d_in[2];
    const int*   tgt  = (const int*)d_in[3];
    const int*   pref = (const int*)d_in[4];
    const float* xr   = (const float*)d_in[5];
    const float* w1   = (const float*)d_in[6];
    const float* b1   = (const float*)d_in[7];
    const float* kl   = (const float*)d_in[8];
    float* out = (float*)d_out;

    // ws layout: xbf | partials | tgtlog | logp | [wbf if it fits]
    const size_t xbf_b  = (size_t)2 * BT * HD * 2;          // 33.55 MB
    const size_t part_b = (size_t)2 * BT * NCHUNK * 2 * 4;  // 16.38 MB
    const size_t tl_b   = (size_t)2 * BT * 4;
    const size_t wbf_b  = (size_t)2 * VD * HD * 2;          // 524.3 MB

    char* wp = (char*)d_ws;
    uint16_t* xbf     = (uint16_t*)wp;                 wp += xbf_b;
    float*    partials = (float*)wp;                   wp += part_b;
    float*    tgtlog   = (float*)wp;                   wp += tl_b;
    float*    logp     = (float*)wp;                   wp += tl_b;
    uint16_t* wbf      = (uint16_t*)wp;
    const bool use_wbf = ws_size >= (xbf_b + part_b + 2 * tl_b + wbf_b);

    hipLaunchKernelGGL(convert_x, dim3(1024), dim3(256), 0, stream, x, xr, xbf);
    if (use_wbf) {
        hipLaunchKernelGGL(convert_w, dim3(4096), dim3(256), 0, stream, w0, w1, wbf);
        hipLaunchKernelGGL(gemm_lse_bf, dim3(NWG2), dim3(512), 0, stream,
                           xbf, wbf, b0, b1, tgt, partials, tgtlog);
    } else {
        hipLaunchKernelGGL(gemm_lse_f32, dim3(8000), dim3(256), 0, stream,
                           xbf, w0, b0, w1, b1, tgt, partials, tgtlog);
    }
    hipLaunchKernelGGL(lse_reduce, dim3(2 * BT / 4), dim3(256), 0, stream,
                       partials, tgtlog, logp);
    hipLaunchKernelGGL(final_loss, dim3(1), dim3(512), 0, stream, logp, tgt, pref, kl, out);
}

// Round 4
// 1543.351 us; speedup vs baseline: 1.4505x; 1.1475x over previous
//
#include <hip/hip_runtime.h>
#include <hip/hip_bf16.h>
#include <stdint.h>

#define HD 4096
#define VD 32000
#define BT 2048        // B*T rows
#define TT 512
#define IGNORE_IDX (-100)

// bf16 8-wave main GEMM geometry
#define BM 256
#define BN 256
#define BKT 64
#define KT (HD / BKT)          // 64 K-tiles
#define NB (VD / BN)           // 125
#define MB (BT / BM)           // 8
#define NWG2 (MB * NB * 2)     // 2000

// partials granularity (64 columns per chunk) — shared with f32 fallback
#define NCHUNK (VD / 64)       // 500

typedef __attribute__((ext_vector_type(8))) short short8;
typedef __attribute__((ext_vector_type(4))) float f32x4;

__device__ __forceinline__ uint16_t f2bf(float f) {
    uint32_t u = __float_as_uint(f);
    u += 0x7FFFu + ((u >> 16) & 1u);   // round-to-nearest-even
    return (uint16_t)(u >> 16);
}

__device__ __forceinline__ void gload16(const void* g, void* l) {
    __builtin_amdgcn_global_load_lds(
        (const __attribute__((address_space(1))) void*)g,
        (__attribute__((address_space(3))) void*)l, 16, 0, 0);
}

// ---------------- kernel 0a: convert x inputs f32 -> bf16 ----------------
__global__ void convert_x(const float* __restrict__ x0, const float* __restrict__ x1,
                          uint16_t* __restrict__ xbf) {
    const int64_t n4 = (int64_t)BT * HD / 4;
    ushort4* o0 = (ushort4*)xbf;
    ushort4* o1 = (ushort4*)(xbf + (int64_t)BT * HD);
    for (int64_t i = blockIdx.x * (int64_t)blockDim.x + threadIdx.x; i < n4;
         i += (int64_t)gridDim.x * blockDim.x) {
        float4 a = ((const float4*)x0)[i];
        float4 b = ((const float4*)x1)[i];
        ushort4 ua, ub;
        ua.x = f2bf(a.x); ua.y = f2bf(a.y); ua.z = f2bf(a.z); ua.w = f2bf(a.w);
        ub.x = f2bf(b.x); ub.y = f2bf(b.y); ub.z = f2bf(b.z); ub.w = f2bf(b.w);
        o0[i] = ua;
        o1[i] = ub;
    }
}

// ---------------- kernel 0b: convert weights f32 -> bf16 ----------------
__global__ void convert_w(const float* __restrict__ w0, const float* __restrict__ w1,
                          uint16_t* __restrict__ wbf) {
    const int64_t n4 = (int64_t)VD * HD / 4;
    ushort4* o0 = (ushort4*)wbf;
    ushort4* o1 = (ushort4*)(wbf + (int64_t)VD * HD);
    for (int64_t i = blockIdx.x * (int64_t)blockDim.x + threadIdx.x; i < n4;
         i += (int64_t)gridDim.x * blockDim.x) {
        float4 a = ((const float4*)w0)[i];
        float4 b = ((const float4*)w1)[i];
        ushort4 ua, ub;
        ua.x = f2bf(a.x); ua.y = f2bf(a.y); ua.z = f2bf(a.z); ua.w = f2bf(a.w);
        ub.x = f2bf(b.x); ub.y = f2bf(b.y); ub.z = f2bf(b.z); ub.w = f2bf(b.w);
        o0[i] = ua;
        o1[i] = ub;
    }
}

// ---------------- main GEMM tile body ----------------
// Per tile: 2 counted waits (vmcnt(4)) + 2 barriers for staging; then 2 k-major
// phases, each = 12 ds_read (immediate-folded offsets) + 32 acc-independent MFMA.
template<int CUR>
__device__ __forceinline__ void tile_body(
    int t,
    const uint16_t* __restrict__ agp, const uint16_t* __restrict__ bgp, int wid,
    const char* pA0, const char* pA1, const char* pB0, const char* pB1,
    uint16_t* As, uint16_t* Bs, f32x4 (&acc)[8][4])
{
    const int nxt = CUR ^ 1;
    const bool more = (t + 1) < KT;
    const int ko = (t + 1) * BKT;

    // ---- wait 1: retire B(t); barrier joins (all waves' B chunks visible) ----
    __builtin_amdgcn_sched_barrier(0);
    asm volatile("s_waitcnt vmcnt(4)" ::: "memory");
    __builtin_amdgcn_sched_barrier(0);
    __builtin_amdgcn_s_barrier();
    __builtin_amdgcn_sched_barrier(0);
    if (more) {
#pragma unroll
        for (int i = 0; i < 4; ++i)
            gload16(bgp + (size_t)i * 8 * HD + ko,
                    (char*)Bs + nxt * 32768 + wid * 4096 + i * 1024);
    }
    // ---- wait 2: retire A(t) ----
    __builtin_amdgcn_sched_barrier(0);
    if (more) { asm volatile("s_waitcnt vmcnt(4)" ::: "memory"); }
    else      { asm volatile("s_waitcnt vmcnt(0)" ::: "memory"); }
    __builtin_amdgcn_sched_barrier(0);
    __builtin_amdgcn_s_barrier();
    __builtin_amdgcn_sched_barrier(0);
    if (more) {
#pragma unroll
        for (int i = 0; i < 4; ++i)
            gload16(agp + (size_t)i * 8 * HD + ko,
                    (char*)As + nxt * 32768 + wid * 4096 + i * 1024);
    }

    // ---- 2 k-major phases ----
#pragma unroll
    for (int ks = 0; ks < 2; ++ks) {
        const char* pA = ks ? pA1 : pA0;
        const char* pB = ks ? pB1 : pB0;
        short8 af[8], bf[4];
#pragma unroll
        for (int mi = 0; mi < 8; ++mi)
            af[mi] = *(const short8*)(pA + mi * 2048 + CUR * 32768);
#pragma unroll
        for (int ni = 0; ni < 4; ++ni)
            bf[ni] = *(const short8*)(pB + ni * 2048 + CUR * 32768);
        __builtin_amdgcn_s_setprio(1);
#pragma unroll
        for (int mi = 0; mi < 8; ++mi)
#pragma unroll
            for (int ni = 0; ni < 4; ++ni)
                acc[mi][ni] = __builtin_amdgcn_mfma_f32_16x16x32_bf16(
                    af[mi], bf[ni], acc[mi][ni], 0, 0, 0);
        __builtin_amdgcn_s_setprio(0);
    }
}

// ---------------- kernel 1 (main): 256x256 counted-vmcnt GEMM + LSE partials ----------------
__global__ __launch_bounds__(512, 2) void gemm_lse_bf(
    const uint16_t* __restrict__ xbf, const uint16_t* __restrict__ wbf,
    const float* __restrict__ b0, const float* __restrict__ b1,
    const int* __restrict__ target,
    float* __restrict__ partials, float* __restrict__ tgtlog)
{
    __shared__ uint16_t As[2 * BM * BKT];  // 64 KB (2 buffers)
    __shared__ uint16_t Bs[2 * BN * BKT];  // 64 KB

    const int orig = blockIdx.x;
    const int wgid = (orig & 7) * (NWG2 / 8) + (orig >> 3);
    const int mb    = wgid & 7;
    const int rest  = wgid >> 3;
    const int nb    = rest % NB;
    const int model = rest / NB;

    const uint16_t* xb = xbf + (size_t)model * BT * HD;
    const uint16_t* wb = wbf + (size_t)model * VD * HD;
    const float* bias  = model ? b1 : b0;

    const int row0 = mb * BM;
    const int c0   = nb * BN;

    const int tid    = threadIdx.x;
    const int lane   = tid & 63;
    const int wid    = tid >> 6;       // 0..7
    const int wr     = wid >> 2;       // 0..1  (M half)
    const int wc     = wid & 3;        // 0..3  (N quarter)

    const int lane15 = lane & 15;
    const int kg     = lane >> 4;
    const int swz    = (lane & 7) << 4;

    // staging addressing (LDS dest linear, global source slot pre-swizzled)
    const int srow8 = lane >> 3;
    const int slot  = (lane & 7) ^ srow8;
    const uint16_t* agp = xb + (size_t)(row0 + wid * 32 + srow8) * HD + slot * 8;
    const uint16_t* bgp = wb + (size_t)(c0   + wid * 32 + srow8) * HD + slot * 8;

    // fragment read base pointers (per-ks); per-frag = +mi*2048 / +ni*2048 and
    // +CUR*32768 — all literal, folded into ds_read offset immediates.
    const int arow_b = wr * 128 + lane15;
    const int brow_b = wc * 64 + lane15;
    const char* pA0 = (const char*)As + ((arow_b * 128 + 0  + kg * 16) ^ swz);
    const char* pA1 = (const char*)As + ((arow_b * 128 + 64 + kg * 16) ^ swz);
    const char* pB0 = (const char*)Bs + ((brow_b * 128 + 0  + kg * 16) ^ swz);
    const char* pB1 = (const char*)Bs + ((brow_b * 128 + 64 + kg * 16) ^ swz);

    f32x4 acc[8][4];
#pragma unroll
    for (int i = 0; i < 8; ++i)
#pragma unroll
        for (int j = 0; j < 4; ++j) acc[i][j] = (f32x4){0.f, 0.f, 0.f, 0.f};

    // prologue: stage tile 0 — B first, then A (issue order defines vmcnt ages)
#pragma unroll
    for (int i = 0; i < 4; ++i)
        gload16(bgp + (size_t)i * 8 * HD, (char*)Bs + wid * 4096 + i * 1024);
#pragma unroll
    for (int i = 0; i < 4; ++i)
        gload16(agp + (size_t)i * 8 * HD, (char*)As + wid * 4096 + i * 1024);

    for (int t2 = 0; t2 < KT; t2 += 2) {
        tile_body<0>(t2,     agp, bgp, wid, pA0, pA1, pB0, pB1, As, Bs, acc);
        tile_body<1>(t2 + 1, agp, bgp, wid, pA0, pA1, pB0, pB1, As, Bs, acc);
    }

    // ---- epilogue: bias, per-row max/sumexp over this wave's 64 cols ----
    float bv4[4];
#pragma unroll
    for (int ni = 0; ni < 4; ++ni) bv4[ni] = bias[c0 + wc * 64 + ni * 16 + lane15];

#pragma unroll
    for (int mi = 0; mi < 8; ++mi) {
        const int grow_base = row0 + wr * 128 + mi * 16 + kg * 4;
#pragma unroll
        for (int j = 0; j < 4; ++j) {
            const int grow = grow_base + j;
            float v[4];
#pragma unroll
            for (int ni = 0; ni < 4; ++ni) v[ni] = acc[mi][ni][j] + bv4[ni];
            float m = fmaxf(fmaxf(v[0], v[1]), fmaxf(v[2], v[3]));
#pragma unroll
            for (int msk = 1; msk < 16; msk <<= 1)
                m = fmaxf(m, __shfl_xor(m, msk));
            float s = __expf(v[0] - m) + __expf(v[1] - m) +
                      __expf(v[2] - m) + __expf(v[3] - m);
#pragma unroll
            for (int msk = 1; msk < 16; msk <<= 1)
                s += __shfl_xor(s, msk);
            const int tg = target[grow];
#pragma unroll
            for (int ni = 0; ni < 4; ++ni) {
                const int gcol = c0 + wc * 64 + ni * 16 + lane15;
                if (tg == gcol) tgtlog[model * BT + grow] = v[ni];
            }
            if (lane15 == 0) {
                const size_t po = ((size_t)(model * BT + grow) * NCHUNK + nb * 4 + wc) * 2;
                partials[po]     = m;
                partials[po + 1] = s;
            }
        }
    }
}

// ---------------- kernel 1 (fallback, f32 weights): R1 structure ----------------
__global__ __launch_bounds__(256) void gemm_lse_f32(
    const uint16_t* __restrict__ xbf,
    const float* __restrict__ w0, const float* __restrict__ b0,
    const float* __restrict__ w1, const float* __restrict__ b1,
    const int* __restrict__ target,
    float* __restrict__ partials, float* __restrict__ tgtlog)
{
    const int orig = blockIdx.x;               // grid 8000
    const int wgid = (orig & 7) * 1000 + (orig >> 3);
    const int mb    = wgid & 7;
    const int rest  = wgid >> 3;
    const int chunk = rest % 500;
    const int model = rest / 500;

    const float* w    = model ? w1 : w0;
    const float* bias = model ? b1 : b0;
    const uint16_t* xb = xbf + (size_t)model * BT * HD;

    const int row0 = mb * 256;
    const int c0   = chunk * 64;

    const int tid  = threadIdx.x;
    const int lane = tid & 63;
    const int wid  = tid >> 6;

    __shared__ uint16_t As_[256 * 64];
    __shared__ uint16_t Bs_[64 * 64];

    f32x4 acc[4][4];
#pragma unroll
    for (int i = 0; i < 4; ++i)
#pragma unroll
        for (int j = 0; j < 4; ++j) acc[i][j] = (f32x4){0.f, 0.f, 0.f, 0.f};

    const int srow8 = lane >> 3;
    const int slot  = (lane & 7) ^ srow8;
    const uint16_t* agsrc = xb + (size_t)(row0 + wid * 64 + srow8) * HD + slot * 8;
    char* aldst = (char*)As_ + wid * 8192;

    const int ss   = tid & 7;
    const int srow = tid >> 3;
    const int swz_w = (srow & 7) << 4;
    const float* bptr = w + (size_t)(c0 + srow) * HD + ss * 8;

    const int lane15 = lane & 15;
    const int kg     = lane >> 4;
    const int swz_r  = (lane & 7) << 4;

    for (int kt = 0; kt < 64; ++kt) {
        const int kofs = kt * 64;
#pragma unroll
        for (int c = 0; c < 8; ++c)
            gload16(agsrc + (size_t)c * 8 * HD + kofs, aldst + c * 1024);
        {
            float4 bv[2][2];
#pragma unroll
            for (int r = 0; r < 2; ++r) {
                const float* p = bptr + (size_t)r * 32 * HD + kofs;
                bv[r][0] = *(const float4*)(p);
                bv[r][1] = *(const float4*)(p + 4);
            }
#pragma unroll
            for (int r = 0; r < 2; ++r) {
                const int row_l = srow + r * 32;
                float fv[8] = {bv[r][0].x, bv[r][0].y, bv[r][0].z, bv[r][0].w,
                               bv[r][1].x, bv[r][1].y, bv[r][1].z, bv[r][1].w};
                uint32_t pk[4];
#pragma unroll
                for (int e = 0; e < 4; ++e)
                    pk[e] = (uint32_t)f2bf(fv[2 * e]) | ((uint32_t)f2bf(fv[2 * e + 1]) << 16);
                const int off = (row_l * 128 + ss * 16) ^ swz_w;
                *(uint4*)((char*)Bs_ + off) = *(uint4*)pk;
            }
        }
        __syncthreads();
#pragma unroll
        for (int ks = 0; ks < 2; ++ks) {
            short8 af[4], bf[4];
#pragma unroll
            for (int mi = 0; mi < 4; ++mi) {
                const int arow = wid * 64 + mi * 16 + lane15;
                const int off = (arow * 128 + ks * 64 + kg * 16) ^ swz_r;
                af[mi] = *(const short8*)((const char*)As_ + off);
            }
#pragma unroll
            for (int ni = 0; ni < 4; ++ni) {
                const int brow = ni * 16 + lane15;
                const int off = (brow * 128 + ks * 64 + kg * 16) ^ swz_r;
                bf[ni] = *(const short8*)((const char*)Bs_ + off);
            }
#pragma unroll
            for (int mi = 0; mi < 4; ++mi)
#pragma unroll
                for (int ni = 0; ni < 4; ++ni)
                    acc[mi][ni] = __builtin_amdgcn_mfma_f32_16x16x32_bf16(
                        af[mi], bf[ni], acc[mi][ni], 0, 0, 0);
        }
        __syncthreads();
    }

    float bv4[4];
#pragma unroll
    for (int ni = 0; ni < 4; ++ni) bv4[ni] = bias[c0 + ni * 16 + lane15];

#pragma unroll
    for (int mi = 0; mi < 4; ++mi) {
        const int grow_base = row0 + wid * 64 + mi * 16 + kg * 4;
#pragma unroll
        for (int j = 0; j < 4; ++j) {
            const int grow = grow_base + j;
            float v[4];
#pragma unroll
            for (int ni = 0; ni < 4; ++ni) v[ni] = acc[mi][ni][j] + bv4[ni];
            float m = fmaxf(fmaxf(v[0], v[1]), fmaxf(v[2], v[3]));
#pragma unroll
            for (int msk = 1; msk < 16; msk <<= 1)
                m = fmaxf(m, __shfl_xor(m, msk));
            float s = __expf(v[0] - m) + __expf(v[1] - m) +
                      __expf(v[2] - m) + __expf(v[3] - m);
#pragma unroll
            for (int msk = 1; msk < 16; msk <<= 1)
                s += __shfl_xor(s, msk);
            const int tg = target[grow];
#pragma unroll
            for (int ni = 0; ni < 4; ++ni) {
                const int gcol = c0 + ni * 16 + lane15;
                if (tg == gcol) tgtlog[model * BT + grow] = v[ni];
            }
            if (lane15 == 0) {
                const size_t po = ((size_t)(model * BT + grow) * NCHUNK + chunk) * 2;
                partials[po]     = m;
                partials[po + 1] = s;
            }
        }
    }
}

// ---------------- kernel 2: combine chunk partials -> lse -> per-token logp ----------------
__global__ void lse_reduce(const float* __restrict__ partials,
                           const float* __restrict__ tgtlog,
                           float* __restrict__ logp) {
    const int gw = blockIdx.x * (blockDim.x >> 6) + (threadIdx.x >> 6);
    if (gw >= 2 * BT) return;
    const int lane = threadIdx.x & 63;
    const float* p = partials + (size_t)gw * NCHUNK * 2;

    float m = -1e30f;
#pragma unroll
    for (int i = 0; i < 8; ++i) {
        const int c = lane + i * 64;
        if (c < NCHUNK) m = fmaxf(m, p[c * 2]);
    }
#pragma unroll
    for (int msk = 1; msk < 64; msk <<= 1) m = fmaxf(m, __shfl_xor(m, msk));
    float s = 0.f;
#pragma unroll
    for (int i = 0; i < 8; ++i) {
        const int c = lane + i * 64;
        if (c < NCHUNK) s += p[c * 2 + 1] * __expf(p[c * 2] - m);
    }
#pragma unroll
    for (int msk = 1; msk < 64; msk <<= 1) s += __shfl_xor(s, msk);
    if (lane == 0) {
        const float lse = m + __logf(s);
        logp[gw] = tgtlog[gw] - lse;
    }
}

// ---------------- kernel 3: KTO loss ----------------
__global__ void final_loss(const float* __restrict__ logp, const int* __restrict__ target,
                           const int* __restrict__ pref, const float* __restrict__ kl,
                           float* __restrict__ out) {
    const int t = threadIdx.x;          // 512 threads
    const int lane = t & 63, wv = t >> 6;
    __shared__ float rp[4][8], rr[4][8], rm[4][8];
#pragma unroll
    for (int b = 0; b < 4; ++b) {
        const int idx = b * TT + t;
        const int tg = target[idx];
        const bool mk = (tg != IGNORE_IDX);
        float lp = mk ? logp[idx] : 0.f;
        float lr = mk ? logp[BT + idx] : 0.f;
        float mc = mk ? 1.f : 0.f;
        for (int off = 32; off; off >>= 1) {
            lp += __shfl_down(lp, off);
            lr += __shfl_down(lr, off);
            mc += __shfl_down(mc, off);
        }
        if (lane == 0) { rp[b][wv] = lp; rr[b][wv] = lr; rm[b][wv] = mc; }
    }
    __syncthreads();
    if (t == 0) {
        float loss = 0.f;
        for (int b = 0; b < 4; ++b) {
            float sp = 0.f, sr = 0.f, sm = 0.f;
            for (int i = 0; i < 8; ++i) { sp += rp[b][i]; sr += rr[b][i]; sm += rm[b][i]; }
            const float denom = fmaxf(sm, 1.f);
            const float lrb = (sp - sr) / denom;
            const float mult = pref[b] ? 1.f : -1.f;
            const float z = 0.1f * (lrb - kl[0]) * mult;
            loss += 1.f / (1.f + __expf(z));   // 1 - sigmoid(z)
        }
        out[0] = loss * 0.25f;
    }
}

extern "C" void kernel_launch(void* const* d_in, const int* in_sizes, int n_in,
                              void* d_out, int out_size, void* d_ws, size_t ws_size,
                              hipStream_t stream) {
    const float* x    = (const float*)d_in[0];
    const float* w0   = (const float*)d_in[1];
    const float* b0   = (const float*)d_in[2];
    const int*   tgt  = (const int*)d_in[3];
    const int*   pref = (const int*)d_in[4];
    const float* xr   = (const float*)d_in[5];
    const float* w1   = (const float*)d_in[6];
    const float* b1   = (const float*)d_in[7];
    const float* kl   = (const float*)d_in[8];
    float* out = (float*)d_out;

    // ws layout: xbf | partials | tgtlog | logp | [wbf if it fits]
    const size_t xbf_b  = (size_t)2 * BT * HD * 2;          // 33.55 MB
    const size_t part_b = (size_t)2 * BT * NCHUNK * 2 * 4;  // 16.38 MB
    const size_t tl_b   = (size_t)2 * BT * 4;
    const size_t wbf_b  = (size_t)2 * VD * HD * 2;          // 524.3 MB

    char* wp = (char*)d_ws;
    uint16_t* xbf     = (uint16_t*)wp;                 wp += xbf_b;
    float*    partials = (float*)wp;                   wp += part_b;
    float*    tgtlog   = (float*)wp;                   wp += tl_b;
    float*    logp     = (float*)wp;                   wp += tl_b;
    uint16_t* wbf      = (uint16_t*)wp;
    const bool use_wbf = ws_size >= (xbf_b + part_b + 2 * tl_b + wbf_b);

    hipLaunchKernelGGL(convert_x, dim3(1024), dim3(256), 0, stream, x, xr, xbf);
    if (use_wbf) {
        hipLaunchKernelGGL(convert_w, dim3(4096), dim3(256), 0, stream, w0, w1, wbf);
        hipLaunchKernelGGL(gemm_lse_bf, dim3(NWG2), dim3(512), 0, stream,
                           xbf, wbf, b0, b1, tgt, partials, tgtlog);
    } else {
        hipLaunchKernelGGL(gemm_lse_f32, dim3(8000), dim3(256), 0, stream,
                           xbf, w0, b0, w1, b1, tgt, partials, tgtlog);
    }
    hipLaunchKernelGGL(lse_reduce, dim3(2 * BT / 4), dim3(256), 0, stream,
                       partials, tgtlog, logp);
    hipLaunchKernelGGL(final_loss, dim3(1), dim3(512), 0, stream, logp, tgt, pref, kl, out);
}

// Round 5
// 1291.358 us; speedup vs baseline: 1.7335x; 1.1951x over previous
//
#include <hip/hip_runtime.h>
#include <hip/hip_bf16.h>
#include <stdint.h>

#define HD 4096
#define VD 32000
#define BT 2048        // B*T rows
#define TT 512
#define IGNORE_IDX (-100)

// bf16 8-wave main GEMM geometry
#define BM 256
#define BN 256
#define BKT 64
#define KT (HD / BKT)          // 64 K-tiles
#define NB (VD / BN)           // 125
#define MB (BT / BM)           // 8
#define NWG2 (MB * NB * 2)     // 2000

// partials granularity (64 columns per chunk) — shared with f32 fallback
#define NCHUNK (VD / 64)       // 500

typedef __attribute__((ext_vector_type(8))) short short8;
typedef __attribute__((ext_vector_type(4))) float f32x4;

__device__ __forceinline__ uint16_t f2bf(float f) {
    uint32_t u = __float_as_uint(f);
    u += 0x7FFFu + ((u >> 16) & 1u);   // round-to-nearest-even
    return (uint16_t)(u >> 16);
}

__device__ __forceinline__ void gload16(const void* g, void* l) {
    __builtin_amdgcn_global_load_lds(
        (const __attribute__((address_space(1))) void*)g,
        (__attribute__((address_space(3))) void*)l, 16, 0, 0);
}

#define SBAR __builtin_amdgcn_sched_barrier(0)

// ---------------- kernel 0a: convert x inputs f32 -> bf16 ----------------
__global__ void convert_x(const float* __restrict__ x0, const float* __restrict__ x1,
                          uint16_t* __restrict__ xbf) {
    const int64_t n4 = (int64_t)BT * HD / 4;
    ushort4* o0 = (ushort4*)xbf;
    ushort4* o1 = (ushort4*)(xbf + (int64_t)BT * HD);
    for (int64_t i = blockIdx.x * (int64_t)blockDim.x + threadIdx.x; i < n4;
         i += (int64_t)gridDim.x * blockDim.x) {
        float4 a = ((const float4*)x0)[i];
        float4 b = ((const float4*)x1)[i];
        ushort4 ua, ub;
        ua.x = f2bf(a.x); ua.y = f2bf(a.y); ua.z = f2bf(a.z); ua.w = f2bf(a.w);
        ub.x = f2bf(b.x); ub.y = f2bf(b.y); ub.z = f2bf(b.z); ub.w = f2bf(b.w);
        o0[i] = ua;
        o1[i] = ub;
    }
}

// ---------------- kernel 0b: convert weights f32 -> bf16 ----------------
__global__ void convert_w(const float* __restrict__ w0, const float* __restrict__ w1,
                          uint16_t* __restrict__ wbf) {
    const int64_t n4 = (int64_t)VD * HD / 4;
    ushort4* o0 = (ushort4*)wbf;
    ushort4* o1 = (ushort4*)(wbf + (int64_t)VD * HD);
    for (int64_t i = blockIdx.x * (int64_t)blockDim.x + threadIdx.x; i < n4;
         i += (int64_t)gridDim.x * blockDim.x) {
        float4 a = ((const float4*)w0)[i];
        float4 b = ((const float4*)w1)[i];
        ushort4 ua, ub;
        ua.x = f2bf(a.x); ua.y = f2bf(a.y); ua.z = f2bf(a.z); ua.w = f2bf(a.w);
        ub.x = f2bf(b.x); ub.y = f2bf(b.y); ub.z = f2bf(b.z); ub.w = f2bf(b.w);
        o0[i] = ua;
        o1[i] = ub;
    }
}

// 16 MFMA cluster (one mi-pair quadrant x K=64), ks-major: 8 independent then 8.
__device__ __forceinline__ void mfma16(
    const short8& a0k0, const short8& a0k1, const short8& a1k0, const short8& a1k1,
    const short8 (&bfr)[4][2], f32x4* acc0, f32x4* acc1)
{
    __builtin_amdgcn_s_setprio(1);
#pragma unroll
    for (int ni = 0; ni < 4; ++ni)
        acc0[ni] = __builtin_amdgcn_mfma_f32_16x16x32_bf16(a0k0, bfr[ni][0], acc0[ni], 0, 0, 0);
#pragma unroll
    for (int ni = 0; ni < 4; ++ni)
        acc1[ni] = __builtin_amdgcn_mfma_f32_16x16x32_bf16(a1k0, bfr[ni][0], acc1[ni], 0, 0, 0);
#pragma unroll
    for (int ni = 0; ni < 4; ++ni)
        acc0[ni] = __builtin_amdgcn_mfma_f32_16x16x32_bf16(a0k1, bfr[ni][1], acc0[ni], 0, 0, 0);
#pragma unroll
    for (int ni = 0; ni < 4; ++ni)
        acc1[ni] = __builtin_amdgcn_mfma_f32_16x16x32_bf16(a1k1, bfr[ni][1], acc1[ni], 0, 0, 0);
    __builtin_amdgcn_s_setprio(0);
}

// ---------------- main GEMM tile body: 4 phases, counted vmcnt ----------------
// Stage order (tile t stages t+1): ph0 B cb0-1, ph1 B cb2-3, ph2 A rb0-1, ph3 A rb2-3.
// Waits: vmcnt(4) end-ph1 (retires prev tile's A rb2-3 before ph2 reads them next tile),
//        vmcnt(2) end-ph3 (retires this tile's B + A rb0-1 before next tile ph0).
template<int CUR>
__device__ __forceinline__ void tile_body(
    int t,
    const uint16_t* __restrict__ agp, const uint16_t* __restrict__ bgp,
    char* aLdst, char* bLdst,
    const char* pA0, const char* pA1, const char* pB0, const char* pB1,
    f32x4 (&acc)[8][4])
{
    constexpr int CB  = CUR * 32768;
    constexpr int NXB = (CUR ^ 1) * 32768;
    const bool more = (t + 1) < KT;
    const int ko = (t + 1) * BKT;

    short8 bfr[4][2];
    short8 af0k0, af0k1, af1k0, af1k1;

#define BARR do { SBAR; __builtin_amdgcn_s_barrier(); SBAR; } while (0)
#define LOAD_AF(mi0)                                                   \
    af0k0 = *(const short8*)(pA0 + (mi0) * 2048 + CB);                 \
    af0k1 = *(const short8*)(pA1 + (mi0) * 2048 + CB);                 \
    af1k0 = *(const short8*)(pA0 + ((mi0) + 1) * 2048 + CB);           \
    af1k1 = *(const short8*)(pA1 + ((mi0) + 1) * 2048 + CB);

    // ---------- phase 0: B-frags + A mi0,1 ; stage B cb0,cb1 ----------
#pragma unroll
    for (int ni = 0; ni < 4; ++ni) {
        bfr[ni][0] = *(const short8*)(pB0 + ni * 2048 + CB);
        bfr[ni][1] = *(const short8*)(pB1 + ni * 2048 + CB);
    }
    LOAD_AF(0);
    if (more) {
        gload16(bgp + (size_t)(0 * 32) * HD + ko, bLdst + NXB + 0 * 4096);
        gload16(bgp + (size_t)(1 * 32) * HD + ko, bLdst + NXB + 1 * 4096);
    }
    BARR;
    mfma16(af0k0, af0k1, af1k0, af1k1, bfr, acc[0], acc[1]);
    BARR;

    // ---------- phase 1: A mi2,3 ; stage B cb2,cb3 ; vmcnt(4) ----------
    LOAD_AF(2);
    if (more) {
        gload16(bgp + (size_t)(2 * 32) * HD + ko, bLdst + NXB + 2 * 4096);
        gload16(bgp + (size_t)(3 * 32) * HD + ko, bLdst + NXB + 3 * 4096);
    }
    BARR;
    mfma16(af0k0, af0k1, af1k0, af1k1, bfr, acc[2], acc[3]);
    SBAR; asm volatile("s_waitcnt vmcnt(4)" ::: "memory"); SBAR;
    BARR;

    // ---------- phase 2: A mi4,5 ; stage A rb0,rb1 ----------
    LOAD_AF(4);
    if (more) {
        gload16(agp + (size_t)(0 * 32) * HD + ko, aLdst + NXB + 0 * 4096);
        gload16(agp + (size_t)(1 * 32) * HD + ko, aLdst + NXB + 1 * 4096);
    }
    BARR;
    mfma16(af0k0, af0k1, af1k0, af1k1, bfr, acc[4], acc[5]);
    BARR;

    // ---------- phase 3: A mi6,7 ; stage A rb2,rb3 ; vmcnt(2|0) ----------
    LOAD_AF(6);
    if (more) {
        gload16(agp + (size_t)(2 * 32) * HD + ko, aLdst + NXB + 2 * 4096);
        gload16(agp + (size_t)(3 * 32) * HD + ko, aLdst + NXB + 3 * 4096);
    }
    BARR;
    mfma16(af0k0, af0k1, af1k0, af1k1, bfr, acc[6], acc[7]);
    SBAR;
    if (more) { asm volatile("s_waitcnt vmcnt(2)" ::: "memory"); }
    else      { asm volatile("s_waitcnt vmcnt(0)" ::: "memory"); }
    SBAR;
    BARR;
#undef LOAD_AF
#undef BARR
}

// ---------------- kernel 1 (main): 256x256 4-phase GEMM + LSE partials ----------------
__global__ __launch_bounds__(512, 2) void gemm_lse_bf(
    const uint16_t* __restrict__ xbf, const uint16_t* __restrict__ wbf,
    const float* __restrict__ b0, const float* __restrict__ b1,
    const int* __restrict__ target,
    float* __restrict__ partials, float* __restrict__ tgtlog)
{
    __shared__ uint16_t As[2 * BM * BKT];  // 64 KB (2 buffers)
    __shared__ uint16_t Bs[2 * BN * BKT];  // 64 KB

    const int orig = blockIdx.x;
    const int wgid = (orig & 7) * (NWG2 / 8) + (orig >> 3);
    const int mb    = wgid & 7;
    const int rest  = wgid >> 3;
    const int nb    = rest % NB;
    const int model = rest / NB;

    const uint16_t* xb = xbf + (size_t)model * BT * HD;
    const uint16_t* wb = wbf + (size_t)model * VD * HD;
    const float* bias  = model ? b1 : b0;

    const int row0 = mb * BM;
    const int c0   = nb * BN;

    const int tid    = threadIdx.x;
    const int lane   = tid & 63;
    const int wid    = tid >> 6;       // 0..7
    const int wr     = wid >> 2;       // 0..1  (M half)
    const int wc     = wid & 3;        // 0..3  (N quarter)

    const int lane15 = lane & 15;
    const int kg     = lane >> 4;
    const int swz    = (lane & 7) << 4;

    // wave-local staging: wave stages ONLY its A-half (rows wr*128..+127) and
    // B-half (rows (wc>>1)*128..+127). Per row-block (32 rows) each of the 4
    // co-staging waves covers 8 rows; LDS dest linear 1KB, source pre-swizzled.
    const int srow8 = lane >> 3;               // 0..7
    const int slot  = (lane & 7) ^ srow8;      // pre-swizzled source slot
    const uint16_t* agp = xb + (size_t)(row0 + wr * 128 + wc * 8 + srow8) * HD + slot * 8;
    const int bq = wr * 2 + (wc & 1);          // 0..3: stager index within B-half
    const uint16_t* bgp = wb + (size_t)(c0 + (wc >> 1) * 128 + bq * 8 + srow8) * HD + slot * 8;
    char* aLdst = (char*)As + wr * 16384 + wc * 1024;          // + j*4096 + buf*32768
    char* bLdst = (char*)Bs + (wc >> 1) * 16384 + bq * 1024;   // + j*4096 + buf*32768

    // fragment read base pointers (ks=0/1); +mi*2048 / +ni*2048, +buf*32768.
    const int arow_b = wr * 128 + lane15;
    const int brow_b = wc * 64 + lane15;
    const char* pA0 = (const char*)As + ((arow_b * 128 + 0  + kg * 16) ^ swz);
    const char* pA1 = (const char*)As + ((arow_b * 128 + 64 + kg * 16) ^ swz);
    const char* pB0 = (const char*)Bs + ((brow_b * 128 + 0  + kg * 16) ^ swz);
    const char* pB1 = (const char*)Bs + ((brow_b * 128 + 64 + kg * 16) ^ swz);

    f32x4 acc[8][4];
#pragma unroll
    for (int i = 0; i < 8; ++i)
#pragma unroll
        for (int j = 0; j < 4; ++j) acc[i][j] = (f32x4){0.f, 0.f, 0.f, 0.f};

    // prologue: stage tile 0 into buf 0, drain, barrier
#pragma unroll
    for (int j = 0; j < 4; ++j)
        gload16(bgp + (size_t)(j * 32) * HD, bLdst + j * 4096);
#pragma unroll
    for (int j = 0; j < 4; ++j)
        gload16(agp + (size_t)(j * 32) * HD, aLdst + j * 4096);
    SBAR; asm volatile("s_waitcnt vmcnt(0)" ::: "memory"); SBAR;
    __builtin_amdgcn_s_barrier();
    SBAR;

    for (int t2 = 0; t2 < KT; t2 += 2) {
        tile_body<0>(t2,     agp, bgp, aLdst, bLdst, pA0, pA1, pB0, pB1, acc);
        tile_body<1>(t2 + 1, agp, bgp, aLdst, bLdst, pA0, pA1, pB0, pB1, acc);
    }

    // ---- epilogue: bias, per-row max/sumexp over this wave's 64 cols ----
    float bv4[4];
#pragma unroll
    for (int ni = 0; ni < 4; ++ni) bv4[ni] = bias[c0 + wc * 64 + ni * 16 + lane15];

#pragma unroll
    for (int mi = 0; mi < 8; ++mi) {
        const int grow_base = row0 + wr * 128 + mi * 16 + kg * 4;
#pragma unroll
        for (int j = 0; j < 4; ++j) {
            const int grow = grow_base + j;
            float v[4];
#pragma unroll
            for (int ni = 0; ni < 4; ++ni) v[ni] = acc[mi][ni][j] + bv4[ni];
            float m = fmaxf(fmaxf(v[0], v[1]), fmaxf(v[2], v[3]));
#pragma unroll
            for (int msk = 1; msk < 16; msk <<= 1)
                m = fmaxf(m, __shfl_xor(m, msk));
            float s = __expf(v[0] - m) + __expf(v[1] - m) +
                      __expf(v[2] - m) + __expf(v[3] - m);
#pragma unroll
            for (int msk = 1; msk < 16; msk <<= 1)
                s += __shfl_xor(s, msk);
            const int tg = target[grow];
#pragma unroll
            for (int ni = 0; ni < 4; ++ni) {
                const int gcol = c0 + wc * 64 + ni * 16 + lane15;
                if (tg == gcol) tgtlog[model * BT + grow] = v[ni];
            }
            if (lane15 == 0) {
                const size_t po = ((size_t)(model * BT + grow) * NCHUNK + nb * 4 + wc) * 2;
                partials[po]     = m;
                partials[po + 1] = s;
            }
        }
    }
}

// ---------------- kernel 1 (fallback, f32 weights): R1 structure ----------------
__global__ __launch_bounds__(256) void gemm_lse_f32(
    const uint16_t* __restrict__ xbf,
    const float* __restrict__ w0, const float* __restrict__ b0,
    const float* __restrict__ w1, const float* __restrict__ b1,
    const int* __restrict__ target,
    float* __restrict__ partials, float* __restrict__ tgtlog)
{
    const int orig = blockIdx.x;               // grid 8000
    const int wgid = (orig & 7) * 1000 + (orig >> 3);
    const int mb    = wgid & 7;
    const int rest  = wgid >> 3;
    const int chunk = rest % 500;
    const int model = rest / 500;

    const float* w    = model ? w1 : w0;
    const float* bias = model ? b1 : b0;
    const uint16_t* xb = xbf + (size_t)model * BT * HD;

    const int row0 = mb * 256;
    const int c0   = chunk * 64;

    const int tid  = threadIdx.x;
    const int lane = tid & 63;
    const int wid  = tid >> 6;

    __shared__ uint16_t As_[256 * 64];
    __shared__ uint16_t Bs_[64 * 64];

    f32x4 acc[4][4];
#pragma unroll
    for (int i = 0; i < 4; ++i)
#pragma unroll
        for (int j = 0; j < 4; ++j) acc[i][j] = (f32x4){0.f, 0.f, 0.f, 0.f};

    const int srow8 = lane >> 3;
    const int slot  = (lane & 7) ^ srow8;
    const uint16_t* agsrc = xb + (size_t)(row0 + wid * 64 + srow8) * HD + slot * 8;
    char* aldst = (char*)As_ + wid * 8192;

    const int ss   = tid & 7;
    const int srow = tid >> 3;
    const int swz_w = (srow & 7) << 4;
    const float* bptr = w + (size_t)(c0 + srow) * HD + ss * 8;

    const int lane15 = lane & 15;
    const int kg     = lane >> 4;
    const int swz_r  = (lane & 7) << 4;

    for (int kt = 0; kt < 64; ++kt) {
        const int kofs = kt * 64;
#pragma unroll
        for (int c = 0; c < 8; ++c)
            gload16(agsrc + (size_t)c * 8 * HD + kofs, aldst + c * 1024);
        {
            float4 bv[2][2];
#pragma unroll
            for (int r = 0; r < 2; ++r) {
                const float* p = bptr + (size_t)r * 32 * HD + kofs;
                bv[r][0] = *(const float4*)(p);
                bv[r][1] = *(const float4*)(p + 4);
            }
#pragma unroll
            for (int r = 0; r < 2; ++r) {
                const int row_l = srow + r * 32;
                float fv[8] = {bv[r][0].x, bv[r][0].y, bv[r][0].z, bv[r][0].w,
                               bv[r][1].x, bv[r][1].y, bv[r][1].z, bv[r][1].w};
                uint32_t pk[4];
#pragma unroll
                for (int e = 0; e < 4; ++e)
                    pk[e] = (uint32_t)f2bf(fv[2 * e]) | ((uint32_t)f2bf(fv[2 * e + 1]) << 16);
                const int off = (row_l * 128 + ss * 16) ^ swz_w;
                *(uint4*)((char*)Bs_ + off) = *(uint4*)pk;
            }
        }
        __syncthreads();
#pragma unroll
        for (int ks = 0; ks < 2; ++ks) {
            short8 af[4], bf[4];
#pragma unroll
            for (int mi = 0; mi < 4; ++mi) {
                const int arow = wid * 64 + mi * 16 + lane15;
                const int off = (arow * 128 + ks * 64 + kg * 16) ^ swz_r;
                af[mi] = *(const short8*)((const char*)As_ + off);
            }
#pragma unroll
            for (int ni = 0; ni < 4; ++ni) {
                const int brow = ni * 16 + lane15;
                const int off = (brow * 128 + ks * 64 + kg * 16) ^ swz_r;
                bf[ni] = *(const short8*)((const char*)Bs_ + off);
            }
#pragma unroll
            for (int mi = 0; mi < 4; ++mi)
#pragma unroll
                for (int ni = 0; ni < 4; ++ni)
                    acc[mi][ni] = __builtin_amdgcn_mfma_f32_16x16x32_bf16(
                        af[mi], bf[ni], acc[mi][ni], 0, 0, 0);
        }
        __syncthreads();
    }

    float bv4[4];
#pragma unroll
    for (int ni = 0; ni < 4; ++ni) bv4[ni] = bias[c0 + ni * 16 + lane15];

#pragma unroll
    for (int mi = 0; mi < 4; ++mi) {
        const int grow_base = row0 + wid * 64 + mi * 16 + kg * 4;
#pragma unroll
        for (int j = 0; j < 4; ++j) {
            const int grow = grow_base + j;
            float v[4];
#pragma unroll
            for (int ni = 0; ni < 4; ++ni) v[ni] = acc[mi][ni][j] + bv4[ni];
            float m = fmaxf(fmaxf(v[0], v[1]), fmaxf(v[2], v[3]));
#pragma unroll
            for (int msk = 1; msk < 16; msk <<= 1)
                m = fmaxf(m, __shfl_xor(m, msk));
            float s = __expf(v[0] - m) + __expf(v[1] - m) +
                      __expf(v[2] - m) + __expf(v[3] - m);
#pragma unroll
            for (int msk = 1; msk < 16; msk <<= 1)
                s += __shfl_xor(s, msk);
            const int tg = target[grow];
#pragma unroll
            for (int ni = 0; ni < 4; ++ni) {
                const int gcol = c0 + ni * 16 + lane15;
                if (tg == gcol) tgtlog[model * BT + grow] = v[ni];
            }
            if (lane15 == 0) {
                const size_t po = ((size_t)(model * BT + grow) * NCHUNK + chunk) * 2;
                partials[po]     = m;
                partials[po + 1] = s;
            }
        }
    }
}

// ---------------- kernel 2: combine chunk partials -> lse -> per-token logp ----------------
__global__ void lse_reduce(const float* __restrict__ partials,
                           const float* __restrict__ tgtlog,
                           float* __restrict__ logp) {
    const int gw = blockIdx.x * (blockDim.x >> 6) + (threadIdx.x >> 6);
    if (gw >= 2 * BT) return;
    const int lane = threadIdx.x & 63;
    const float* p = partials + (size_t)gw * NCHUNK * 2;

    float m = -1e30f;
#pragma unroll
    for (int i = 0; i < 8; ++i) {
        const int c = lane + i * 64;
        if (c < NCHUNK) m = fmaxf(m, p[c * 2]);
    }
#pragma unroll
    for (int msk = 1; msk < 64; msk <<= 1) m = fmaxf(m, __shfl_xor(m, msk));
    float s = 0.f;
#pragma unroll
    for (int i = 0; i < 8; ++i) {
        const int c = lane + i * 64;
        if (c < NCHUNK) s += p[c * 2 + 1] * __expf(p[c * 2] - m);
    }
#pragma unroll
    for (int msk = 1; msk < 64; msk <<= 1) s += __shfl_xor(s, msk);
    if (lane == 0) {
        const float lse = m + __logf(s);
        logp[gw] = tgtlog[gw] - lse;
    }
}

// ---------------- kernel 3: KTO loss ----------------
__global__ void final_loss(const float* __restrict__ logp, const int* __restrict__ target,
                           const int* __restrict__ pref, const float* __restrict__ kl,
                           float* __restrict__ out) {
    const int t = threadIdx.x;          // 512 threads
    const int lane = t & 63, wv = t >> 6;
    __shared__ float rp[4][8], rr[4][8], rm[4][8];
#pragma unroll
    for (int b = 0; b < 4; ++b) {
        const int idx = b * TT + t;
        const int tg = target[idx];
        const bool mk = (tg != IGNORE_IDX);
        float lp = mk ? logp[idx] : 0.f;
        float lr = mk ? logp[BT + idx] : 0.f;
        float mc = mk ? 1.f : 0.f;
        for (int off = 32; off; off >>= 1) {
            lp += __shfl_down(lp, off);
            lr += __shfl_down(lr, off);
            mc += __shfl_down(mc, off);
        }
        if (lane == 0) { rp[b][wv] = lp; rr[b][wv] = lr; rm[b][wv] = mc; }
    }
    __syncthreads();
    if (t == 0) {
        float loss = 0.f;
        for (int b = 0; b < 4; ++b) {
            float sp = 0.f, sr = 0.f, sm = 0.f;
            for (int i = 0; i < 8; ++i) { sp += rp[b][i]; sr += rr[b][i]; sm += rm[b][i]; }
            const float denom = fmaxf(sm, 1.f);
            const float lrb = (sp - sr) / denom;
            const float mult = pref[b] ? 1.f : -1.f;
            const float z = 0.1f * (lrb - kl[0]) * mult;
            loss += 1.f / (1.f + __expf(z));   // 1 - sigmoid(z)
        }
        out[0] = loss * 0.25f;
    }
}

extern "C" void kernel_launch(void* const* d_in, const int* in_sizes, int n_in,
                              void* d_out, int out_size, void* d_ws, size_t ws_size,
                              hipStream_t stream) {
    const float* x    = (const float*)d_in[0];
    const float* w0   = (const float*)d_in[1];
    const float* b0   = (const float*)d_in[2];
    const int*   tgt  = (const int*)d_in[3];
    const int*   pref = (const int*)d_in[4];
    const float* xr   = (const float*)d_in[5];
    const float* w1   = (const float*)d_in[6];
    const float* b1   = (const float*)d_in[7];
    const float* kl   = (const float*)d_in[8];
    float* out = (float*)d_out;

    // ws layout: xbf | partials | tgtlog | logp | [wbf if it fits]
    const size_t xbf_b  = (size_t)2 * BT * HD * 2;          // 33.55 MB
    const size_t part_b = (size_t)2 * BT * NCHUNK * 2 * 4;  // 16.38 MB
    const size_t tl_b   = (size_t)2 * BT * 4;
    const size_t wbf_b  = (size_t)2 * VD * HD * 2;          // 524.3 MB

    char* wp = (char*)d_ws;
    uint16_t* xbf     = (uint16_t*)wp;                 wp += xbf_b;
    float*    partials = (float*)wp;                   wp += part_b;
    float*    tgtlog   = (float*)wp;                   wp += tl_b;
    float*    logp     = (float*)wp;                   wp += tl_b;
    uint16_t* wbf      = (uint16_t*)wp;
    const bool use_wbf = ws_size >= (xbf_b + part_b + 2 * tl_b + wbf_b);

    hipLaunchKernelGGL(convert_x, dim3(1024), dim3(256), 0, stream, x, xr, xbf);
    if (use_wbf) {
        hipLaunchKernelGGL(convert_w, dim3(4096), dim3(256), 0, stream, w0, w1, wbf);
        hipLaunchKernelGGL(gemm_lse_bf, dim3(NWG2), dim3(512), 0, stream,
                           xbf, wbf, b0, b1, tgt, partials, tgtlog);
    } else {
        hipLaunchKernelGGL(gemm_lse_f32, dim3(8000), dim3(256), 0, stream,
                           xbf, w0, b0, w1, b1, tgt, partials, tgtlog);
    }
    hipLaunchKernelGGL(lse_reduce, dim3(2 * BT / 4), dim3(256), 0, stream,
                       partials, tgtlog, logp);
    hipLaunchKernelGGL(final_loss, dim3(1), dim3(512), 0, stream, logp, tgt, pref, kl, out);
}

// Round 6
// 1274.750 us; speedup vs baseline: 1.7561x; 1.0130x over previous
//
#include <hip/hip_runtime.h>
#include <hip/hip_bf16.h>
#include <stdint.h>

#define HD 4096
#define VD 32000
#define BT 2048        // B*T rows
#define TT 512
#define IGNORE_IDX (-100)

// bf16 8-wave main GEMM geometry
#define BM 256
#define BN 256
#define BKT 64
#define KT (HD / BKT)          // 64 K-tiles
#define NB (VD / BN)           // 125
#define MB (BT / BM)           // 8
#define NWG2 (MB * NB * 2)     // 2000

// partials granularity (64 columns per chunk) — shared with f32 fallback
#define NCHUNK (VD / 64)       // 500

typedef __attribute__((ext_vector_type(8))) short short8;
typedef __attribute__((ext_vector_type(4))) float f32x4;

__device__ __forceinline__ uint16_t f2bf(float f) {
    uint32_t u = __float_as_uint(f);
    u += 0x7FFFu + ((u >> 16) & 1u);   // round-to-nearest-even
    return (uint16_t)(u >> 16);
}

__device__ __forceinline__ void gload16(const void* g, void* l) {
    __builtin_amdgcn_global_load_lds(
        (const __attribute__((address_space(1))) void*)g,
        (__attribute__((address_space(3))) void*)l, 16, 0, 0);
}

#define SBAR __builtin_amdgcn_sched_barrier(0)

// ---------------- kernel 0a: convert x inputs f32 -> bf16 ----------------
__global__ void convert_x(const float* __restrict__ x0, const float* __restrict__ x1,
                          uint16_t* __restrict__ xbf) {
    const int64_t n4 = (int64_t)BT * HD / 4;
    ushort4* o0 = (ushort4*)xbf;
    ushort4* o1 = (ushort4*)(xbf + (int64_t)BT * HD);
    for (int64_t i = blockIdx.x * (int64_t)blockDim.x + threadIdx.x; i < n4;
         i += (int64_t)gridDim.x * blockDim.x) {
        float4 a = ((const float4*)x0)[i];
        float4 b = ((const float4*)x1)[i];
        ushort4 ua, ub;
        ua.x = f2bf(a.x); ua.y = f2bf(a.y); ua.z = f2bf(a.z); ua.w = f2bf(a.w);
        ub.x = f2bf(b.x); ub.y = f2bf(b.y); ub.z = f2bf(b.z); ub.w = f2bf(b.w);
        o0[i] = ua;
        o1[i] = ub;
    }
}

// ---------------- kernel 0b: convert weights f32 -> bf16 ----------------
__global__ void convert_w(const float* __restrict__ w0, const float* __restrict__ w1,
                          uint16_t* __restrict__ wbf) {
    const int64_t n4 = (int64_t)VD * HD / 4;
    ushort4* o0 = (ushort4*)wbf;
    ushort4* o1 = (ushort4*)(wbf + (int64_t)VD * HD);
    for (int64_t i = blockIdx.x * (int64_t)blockDim.x + threadIdx.x; i < n4;
         i += (int64_t)gridDim.x * blockDim.x) {
        float4 a = ((const float4*)w0)[i];
        float4 b = ((const float4*)w1)[i];
        ushort4 ua, ub;
        ua.x = f2bf(a.x); ua.y = f2bf(a.y); ua.z = f2bf(a.z); ua.w = f2bf(a.w);
        ub.x = f2bf(b.x); ub.y = f2bf(b.y); ub.z = f2bf(b.z); ub.w = f2bf(b.w);
        o0[i] = ua;
        o1[i] = ub;
    }
}

// 16 MFMA cluster (one mi-pair quadrant x K=64), ks-major: 8 independent then 8.
__device__ __forceinline__ void mfma16(
    const short8& a0k0, const short8& a0k1, const short8& a1k0, const short8& a1k1,
    const short8 (&bfr)[4][2], f32x4* acc0, f32x4* acc1)
{
    __builtin_amdgcn_s_setprio(1);
#pragma unroll
    for (int ni = 0; ni < 4; ++ni)
        acc0[ni] = __builtin_amdgcn_mfma_f32_16x16x32_bf16(a0k0, bfr[ni][0], acc0[ni], 0, 0, 0);
#pragma unroll
    for (int ni = 0; ni < 4; ++ni)
        acc1[ni] = __builtin_amdgcn_mfma_f32_16x16x32_bf16(a1k0, bfr[ni][0], acc1[ni], 0, 0, 0);
#pragma unroll
    for (int ni = 0; ni < 4; ++ni)
        acc0[ni] = __builtin_amdgcn_mfma_f32_16x16x32_bf16(a0k1, bfr[ni][1], acc0[ni], 0, 0, 0);
#pragma unroll
    for (int ni = 0; ni < 4; ++ni)
        acc1[ni] = __builtin_amdgcn_mfma_f32_16x16x32_bf16(a1k1, bfr[ni][1], acc1[ni], 0, 0, 0);
    __builtin_amdgcn_s_setprio(0);
}

// ---------------- main GEMM tile body: 4 phases, hoisted ds_reads + counted waits ----------------
// Phase p issues phase p+1's A-frag ds_reads (reg double-buffer setA/setB) so the
// MFMA-entry lgkmcnt(4) is pre-satisfied. vmcnt ledger (steady state; entry = {rb2,rb3}):
//   ph0 +cb01 -> 4, wait vmcnt(2) retires rb2,rb3 (BEFORE ph1 issues reads of rows 64-95)
//   ph1 +cb23 -> 4 ; ph2 +rb01 -> 6 ; ph3 +rb23 -> 8, wait vmcnt(2) retires cb0-3+rb01.
template<int CUR>
__device__ __forceinline__ void tile_body(
    int t,
    const uint16_t* __restrict__ agp, const uint16_t* __restrict__ bgp,
    char* aLdst, char* bLdst,
    const char* pA0, const char* pA1, const char* pB0, const char* pB1,
    f32x4 (&acc)[8][4])
{
    constexpr int CB  = CUR * 32768;
    constexpr int NXB = (CUR ^ 1) * 32768;
    const bool more = (t + 1) < KT;
    const int ko = (t + 1) * BKT;

    short8 bfr[4][2];
    short8 afA0, afA1, afA2, afA3;   // reg set A (mi pair p, ks0/ks1 interleaved)
    short8 afB0, afB1, afB2, afB3;   // reg set B

#define BARR do { SBAR; __builtin_amdgcn_s_barrier(); SBAR; } while (0)
#define RD_SETA(mi0)                                                   \
    afA0 = *(const short8*)(pA0 + (mi0) * 2048 + CB);                  \
    afA1 = *(const short8*)(pA1 + (mi0) * 2048 + CB);                  \
    afA2 = *(const short8*)(pA0 + ((mi0) + 1) * 2048 + CB);           \
    afA3 = *(const short8*)(pA1 + ((mi0) + 1) * 2048 + CB);
#define RD_SETB(mi0)                                                   \
    afB0 = *(const short8*)(pA0 + (mi0) * 2048 + CB);                  \
    afB1 = *(const short8*)(pA1 + (mi0) * 2048 + CB);                  \
    afB2 = *(const short8*)(pA0 + ((mi0) + 1) * 2048 + CB);           \
    afB3 = *(const short8*)(pA1 + ((mi0) + 1) * 2048 + CB);

    // ---------- phase 0: read B-frags(8) + A mi0,1 (setA) + A mi2,3 (setB); stage cb0,cb1 ----------
#pragma unroll
    for (int ni = 0; ni < 4; ++ni) {
        bfr[ni][0] = *(const short8*)(pB0 + ni * 2048 + CB);
        bfr[ni][1] = *(const short8*)(pB1 + ni * 2048 + CB);
    }
    RD_SETA(0);
    RD_SETB(2);
    if (more) {
        gload16(bgp + (size_t)(0 * 32) * HD + ko, bLdst + NXB + 0 * 4096);
        gload16(bgp + (size_t)(1 * 32) * HD + ko, bLdst + NXB + 1 * 4096);
    }
    BARR;
    asm volatile("s_waitcnt lgkmcnt(4)" ::: "memory"); SBAR;   // bfr+setA done; setB in flight
    mfma16(afA0, afA1, afA2, afA3, bfr, acc[0], acc[1]);
    SBAR; asm volatile("s_waitcnt vmcnt(2)" ::: "memory"); SBAR; // retire rb2,rb3(t)
    BARR;

    // ---------- phase 1: read A mi4,5 (setA); stage cb2,cb3 ----------
    RD_SETA(4);
    if (more) {
        gload16(bgp + (size_t)(2 * 32) * HD + ko, bLdst + NXB + 2 * 4096);
        gload16(bgp + (size_t)(3 * 32) * HD + ko, bLdst + NXB + 3 * 4096);
    }
    BARR;
    asm volatile("s_waitcnt lgkmcnt(4)" ::: "memory"); SBAR;   // setB done; setA in flight
    mfma16(afB0, afB1, afB2, afB3, bfr, acc[2], acc[3]);
    BARR;

    // ---------- phase 2: read A mi6,7 (setB); stage rb0,rb1 ----------
    RD_SETB(6);
    if (more) {
        gload16(agp + (size_t)(0 * 32) * HD + ko, aLdst + NXB + 0 * 4096);
        gload16(agp + (size_t)(1 * 32) * HD + ko, aLdst + NXB + 1 * 4096);
    }
    BARR;
    asm volatile("s_waitcnt lgkmcnt(4)" ::: "memory"); SBAR;   // setA done; setB in flight
    mfma16(afA0, afA1, afA2, afA3, bfr, acc[4], acc[5]);
    BARR;

    // ---------- phase 3: stage rb2,rb3 ; vmcnt(2|0) ----------
    if (more) {
        gload16(agp + (size_t)(2 * 32) * HD + ko, aLdst + NXB + 2 * 4096);
        gload16(agp + (size_t)(3 * 32) * HD + ko, aLdst + NXB + 3 * 4096);
    }
    BARR;
    asm volatile("s_waitcnt lgkmcnt(0)" ::: "memory"); SBAR;
    mfma16(afB0, afB1, afB2, afB3, bfr, acc[6], acc[7]);
    SBAR;
    if (more) { asm volatile("s_waitcnt vmcnt(2)" ::: "memory"); }
    else      { asm volatile("s_waitcnt vmcnt(0)" ::: "memory"); }
    SBAR;
    BARR;
#undef RD_SETA
#undef RD_SETB
#undef BARR
}

// ---------------- kernel 1 (main): 256x256 4-phase GEMM + LSE partials ----------------
__global__ __launch_bounds__(512, 2) void gemm_lse_bf(
    const uint16_t* __restrict__ xbf, const uint16_t* __restrict__ wbf,
    const float* __restrict__ b0, const float* __restrict__ b1,
    const int* __restrict__ target,
    float* __restrict__ partials, float* __restrict__ tgtlog)
{
    __shared__ uint16_t As[2 * BM * BKT];  // 64 KB (2 buffers)
    __shared__ uint16_t Bs[2 * BN * BKT];  // 64 KB

    const int orig = blockIdx.x;
    const int wgid = (orig & 7) * (NWG2 / 8) + (orig >> 3);
    const int mb    = wgid & 7;
    const int rest  = wgid >> 3;
    const int nb    = rest % NB;
    const int model = rest / NB;

    const uint16_t* xb = xbf + (size_t)model * BT * HD;
    const uint16_t* wb = wbf + (size_t)model * VD * HD;
    const float* bias  = model ? b1 : b0;

    const int row0 = mb * BM;
    const int c0   = nb * BN;

    const int tid    = threadIdx.x;
    const int lane   = tid & 63;
    const int wid    = tid >> 6;       // 0..7
    const int wr     = wid >> 2;       // 0..1  (M half)
    const int wc     = wid & 3;        // 0..3  (N quarter)

    const int lane15 = lane & 15;
    const int kg     = lane >> 4;
    const int swz    = (lane & 7) << 4;

    // wave-local staging: wave stages ONLY its A-half (rows wr*128..+127) and
    // B-half (rows (wc>>1)*128..+127). Per row-block (32 rows) each of the 4
    // co-staging waves covers 8 rows; LDS dest linear 1KB, source pre-swizzled.
    const int srow8 = lane >> 3;               // 0..7
    const int slot  = (lane & 7) ^ srow8;      // pre-swizzled source slot
    const uint16_t* agp = xb + (size_t)(row0 + wr * 128 + wc * 8 + srow8) * HD + slot * 8;
    const int bq = wr * 2 + (wc & 1);          // 0..3: stager index within B-half
    const uint16_t* bgp = wb + (size_t)(c0 + (wc >> 1) * 128 + bq * 8 + srow8) * HD + slot * 8;
    char* aLdst = (char*)As + wr * 16384 + wc * 1024;          // + j*4096 + buf*32768
    char* bLdst = (char*)Bs + (wc >> 1) * 16384 + bq * 1024;   // + j*4096 + buf*32768

    // fragment read base pointers (ks=0/1); +mi*2048 / +ni*2048, +buf*32768.
    const int arow_b = wr * 128 + lane15;
    const int brow_b = wc * 64 + lane15;
    const char* pA0 = (const char*)As + ((arow_b * 128 + 0  + kg * 16) ^ swz);
    const char* pA1 = (const char*)As + ((arow_b * 128 + 64 + kg * 16) ^ swz);
    const char* pB0 = (const char*)Bs + ((brow_b * 128 + 0  + kg * 16) ^ swz);
    const char* pB1 = (const char*)Bs + ((brow_b * 128 + 64 + kg * 16) ^ swz);

    f32x4 acc[8][4];
#pragma unroll
    for (int i = 0; i < 8; ++i)
#pragma unroll
        for (int j = 0; j < 4; ++j) acc[i][j] = (f32x4){0.f, 0.f, 0.f, 0.f};

    // prologue: stage tile 0 into buf 0, drain, barrier
#pragma unroll
    for (int j = 0; j < 4; ++j)
        gload16(bgp + (size_t)(j * 32) * HD, bLdst + j * 4096);
#pragma unroll
    for (int j = 0; j < 4; ++j)
        gload16(agp + (size_t)(j * 32) * HD, aLdst + j * 4096);
    SBAR; asm volatile("s_waitcnt vmcnt(0)" ::: "memory"); SBAR;
    __builtin_amdgcn_s_barrier();
    SBAR;

    for (int t2 = 0; t2 < KT; t2 += 2) {
        tile_body<0>(t2,     agp, bgp, aLdst, bLdst, pA0, pA1, pB0, pB1, acc);
        tile_body<1>(t2 + 1, agp, bgp, aLdst, bLdst, pA0, pA1, pB0, pB1, acc);
    }

    // ---- epilogue: bias, per-row max/sumexp over this wave's 64 cols ----
    float bv4[4];
#pragma unroll
    for (int ni = 0; ni < 4; ++ni) bv4[ni] = bias[c0 + wc * 64 + ni * 16 + lane15];

#pragma unroll
    for (int mi = 0; mi < 8; ++mi) {
        const int grow_base = row0 + wr * 128 + mi * 16 + kg * 4;
#pragma unroll
        for (int j = 0; j < 4; ++j) {
            const int grow = grow_base + j;
            float v[4];
#pragma unroll
            for (int ni = 0; ni < 4; ++ni) v[ni] = acc[mi][ni][j] + bv4[ni];
            float m = fmaxf(fmaxf(v[0], v[1]), fmaxf(v[2], v[3]));
#pragma unroll
            for (int msk = 1; msk < 16; msk <<= 1)
                m = fmaxf(m, __shfl_xor(m, msk));
            float s = __expf(v[0] - m) + __expf(v[1] - m) +
                      __expf(v[2] - m) + __expf(v[3] - m);
#pragma unroll
            for (int msk = 1; msk < 16; msk <<= 1)
                s += __shfl_xor(s, msk);
            const int tg = target[grow];
#pragma unroll
            for (int ni = 0; ni < 4; ++ni) {
                const int gcol = c0 + wc * 64 + ni * 16 + lane15;
                if (tg == gcol) tgtlog[model * BT + grow] = v[ni];
            }
            if (lane15 == 0) {
                const size_t po = ((size_t)(model * BT + grow) * NCHUNK + nb * 4 + wc) * 2;
                partials[po]     = m;
                partials[po + 1] = s;
            }
        }
    }
}

// ---------------- kernel 1 (fallback, f32 weights): R1 structure ----------------
__global__ __launch_bounds__(256) void gemm_lse_f32(
    const uint16_t* __restrict__ xbf,
    const float* __restrict__ w0, const float* __restrict__ b0,
    const float* __restrict__ w1, const float* __restrict__ b1,
    const int* __restrict__ target,
    float* __restrict__ partials, float* __restrict__ tgtlog)
{
    const int orig = blockIdx.x;               // grid 8000
    const int wgid = (orig & 7) * 1000 + (orig >> 3);
    const int mb    = wgid & 7;
    const int rest  = wgid >> 3;
    const int chunk = rest % 500;
    const int model = rest / 500;

    const float* w    = model ? w1 : w0;
    const float* bias = model ? b1 : b0;
    const uint16_t* xb = xbf + (size_t)model * BT * HD;

    const int row0 = mb * 256;
    const int c0   = chunk * 64;

    const int tid  = threadIdx.x;
    const int lane = tid & 63;
    const int wid  = tid >> 6;

    __shared__ uint16_t As_[256 * 64];
    __shared__ uint16_t Bs_[64 * 64];

    f32x4 acc[4][4];
#pragma unroll
    for (int i = 0; i < 4; ++i)
#pragma unroll
        for (int j = 0; j < 4; ++j) acc[i][j] = (f32x4){0.f, 0.f, 0.f, 0.f};

    const int srow8 = lane >> 3;
    const int slot  = (lane & 7) ^ srow8;
    const uint16_t* agsrc = xb + (size_t)(row0 + wid * 64 + srow8) * HD + slot * 8;
    char* aldst = (char*)As_ + wid * 8192;

    const int ss   = tid & 7;
    const int srow = tid >> 3;
    const int swz_w = (srow & 7) << 4;
    const float* bptr = w + (size_t)(c0 + srow) * HD + ss * 8;

    const int lane15 = lane & 15;
    const int kg     = lane >> 4;
    const int swz_r  = (lane & 7) << 4;

    for (int kt = 0; kt < 64; ++kt) {
        const int kofs = kt * 64;
#pragma unroll
        for (int c = 0; c < 8; ++c)
            gload16(agsrc + (size_t)c * 8 * HD + kofs, aldst + c * 1024);
        {
            float4 bv[2][2];
#pragma unroll
            for (int r = 0; r < 2; ++r) {
                const float* p = bptr + (size_t)r * 32 * HD + kofs;
                bv[r][0] = *(const float4*)(p);
                bv[r][1] = *(const float4*)(p + 4);
            }
#pragma unroll
            for (int r = 0; r < 2; ++r) {
                const int row_l = srow + r * 32;
                float fv[8] = {bv[r][0].x, bv[r][0].y, bv[r][0].z, bv[r][0].w,
                               bv[r][1].x, bv[r][1].y, bv[r][1].z, bv[r][1].w};
                uint32_t pk[4];
#pragma unroll
                for (int e = 0; e < 4; ++e)
                    pk[e] = (uint32_t)f2bf(fv[2 * e]) | ((uint32_t)f2bf(fv[2 * e + 1]) << 16);
                const int off = (row_l * 128 + ss * 16) ^ swz_w;
                *(uint4*)((char*)Bs_ + off) = *(uint4*)pk;
            }
        }
        __syncthreads();
#pragma unroll
        for (int ks = 0; ks < 2; ++ks) {
            short8 af[4], bf[4];
#pragma unroll
            for (int mi = 0; mi < 4; ++mi) {
                const int arow = wid * 64 + mi * 16 + lane15;
                const int off = (arow * 128 + ks * 64 + kg * 16) ^ swz_r;
                af[mi] = *(const short8*)((const char*)As_ + off);
            }
#pragma unroll
            for (int ni = 0; ni < 4; ++ni) {
                const int brow = ni * 16 + lane15;
                const int off = (brow * 128 + ks * 64 + kg * 16) ^ swz_r;
                bf[ni] = *(const short8*)((const char*)Bs_ + off);
            }
#pragma unroll
            for (int mi = 0; mi < 4; ++mi)
#pragma unroll
                for (int ni = 0; ni < 4; ++ni)
                    acc[mi][ni] = __builtin_amdgcn_mfma_f32_16x16x32_bf16(
                        af[mi], bf[ni], acc[mi][ni], 0, 0, 0);
        }
        __syncthreads();
    }

    float bv4[4];
#pragma unroll
    for (int ni = 0; ni < 4; ++ni) bv4[ni] = bias[c0 + ni * 16 + lane15];

#pragma unroll
    for (int mi = 0; mi < 4; ++mi) {
        const int grow_base = row0 + wid * 64 + mi * 16 + kg * 4;
#pragma unroll
        for (int j = 0; j < 4; ++j) {
            const int grow = grow_base + j;
            float v[4];
#pragma unroll
            for (int ni = 0; ni < 4; ++ni) v[ni] = acc[mi][ni][j] + bv4[ni];
            float m = fmaxf(fmaxf(v[0], v[1]), fmaxf(v[2], v[3]));
#pragma unroll
            for (int msk = 1; msk < 16; msk <<= 1)
                m = fmaxf(m, __shfl_xor(m, msk));
            float s = __expf(v[0] - m) + __expf(v[1] - m) +
                      __expf(v[2] - m) + __expf(v[3] - m);
#pragma unroll
            for (int msk = 1; msk < 16; msk <<= 1)
                s += __shfl_xor(s, msk);
            const int tg = target[grow];
#pragma unroll
            for (int ni = 0; ni < 4; ++ni) {
                const int gcol = c0 + ni * 16 + lane15;
                if (tg == gcol) tgtlog[model * BT + grow] = v[ni];
            }
            if (lane15 == 0) {
                const size_t po = ((size_t)(model * BT + grow) * NCHUNK + chunk) * 2;
                partials[po]     = m;
                partials[po + 1] = s;
            }
        }
    }
}

// ---------------- kernel 2: combine chunk partials -> lse -> per-token logp ----------------
__global__ void lse_reduce(const float* __restrict__ partials,
                           const float* __restrict__ tgtlog,
                           float* __restrict__ logp) {
    const int gw = blockIdx.x * (blockDim.x >> 6) + (threadIdx.x >> 6);
    if (gw >= 2 * BT) return;
    const int lane = threadIdx.x & 63;
    const float* p = partials + (size_t)gw * NCHUNK * 2;

    float m = -1e30f;
#pragma unroll
    for (int i = 0; i < 8; ++i) {
        const int c = lane + i * 64;
        if (c < NCHUNK) m = fmaxf(m, p[c * 2]);
    }
#pragma unroll
    for (int msk = 1; msk < 64; msk <<= 1) m = fmaxf(m, __shfl_xor(m, msk));
    float s = 0.f;
#pragma unroll
    for (int i = 0; i < 8; ++i) {
        const int c = lane + i * 64;
        if (c < NCHUNK) s += p[c * 2 + 1] * __expf(p[c * 2] - m);
    }
#pragma unroll
    for (int msk = 1; msk < 64; msk <<= 1) s += __shfl_xor(s, msk);
    if (lane == 0) {
        const float lse = m + __logf(s);
        logp[gw] = tgtlog[gw] - lse;
    }
}

// ---------------- kernel 3: KTO loss ----------------
__global__ void final_loss(const float* __restrict__ logp, const int* __restrict__ target,
                           const int* __restrict__ pref, const float* __restrict__ kl,
                           float* __restrict__ out) {
    const int t = threadIdx.x;          // 512 threads
    const int lane = t & 63, wv = t >> 6;
    __shared__ float rp[4][8], rr[4][8], rm[4][8];
#pragma unroll
    for (int b = 0; b < 4; ++b) {
        const int idx = b * TT + t;
        const int tg = target[idx];
        const bool mk = (tg != IGNORE_IDX);
        float lp = mk ? logp[idx] : 0.f;
        float lr = mk ? logp[BT + idx] : 0.f;
        float mc = mk ? 1.f : 0.f;
        for (int off = 32; off; off >>= 1) {
            lp += __shfl_down(lp, off);
            lr += __shfl_down(lr, off);
            mc += __shfl_down(mc, off);
        }
        if (lane == 0) { rp[b][wv] = lp; rr[b][wv] = lr; rm[b][wv] = mc; }
    }
    __syncthreads();
    if (t == 0) {
        float loss = 0.f;
        for (int b = 0; b < 4; ++b) {
            float sp = 0.f, sr = 0.f, sm = 0.f;
            for (int i = 0; i < 8; ++i) { sp += rp[b][i]; sr += rr[b][i]; sm += rm[b][i]; }
            const float denom = fmaxf(sm, 1.f);
            const float lrb = (sp - sr) / denom;
            const float mult = pref[b] ? 1.f : -1.f;
            const float z = 0.1f * (lrb - kl[0]) * mult;
            loss += 1.f / (1.f + __expf(z));   // 1 - sigmoid(z)
        }
        out[0] = loss * 0.25f;
    }
}

extern "C" void kernel_launch(void* const* d_in, const int* in_sizes, int n_in,
                              void* d_out, int out_size, void* d_ws, size_t ws_size,
                              hipStream_t stream) {
    const float* x    = (const float*)d_in[0];
    const float* w0   = (const float*)d_in[1];
    const float* b0   = (const float*)d_in[2];
    const int*   tgt  = (const int*)d_in[3];
    const int*   pref = (const int*)d_in[4];
    const float* xr   = (const float*)d_in[5];
    const float* w1   = (const float*)d_in[6];
    const float* b1   = (const float*)d_in[7];
    const float* kl   = (const float*)d_in[8];
    float* out = (float*)d_out;

    // ws layout: xbf | partials | tgtlog | logp | [wbf if it fits]
    const size_t xbf_b  = (size_t)2 * BT * HD * 2;          // 33.55 MB
    const size_t part_b = (size_t)2 * BT * NCHUNK * 2 * 4;  // 16.38 MB
    const size_t tl_b   = (size_t)2 * BT * 4;
    const size_t wbf_b  = (size_t)2 * VD * HD * 2;          // 524.3 MB

    char* wp = (char*)d_ws;
    uint16_t* xbf     = (uint16_t*)wp;                 wp += xbf_b;
    float*    partials = (float*)wp;                   wp += part_b;
    float*    tgtlog   = (float*)wp;                   wp += tl_b;
    float*    logp     = (float*)wp;                   wp += tl_b;
    uint16_t* wbf      = (uint16_t*)wp;
    const bool use_wbf = ws_size >= (xbf_b + part_b + 2 * tl_b + wbf_b);

    hipLaunchKernelGGL(convert_x, dim3(1024), dim3(256), 0, stream, x, xr, xbf);
    if (use_wbf) {
        hipLaunchKernelGGL(convert_w, dim3(4096), dim3(256), 0, stream, w0, w1, wbf);
        hipLaunchKernelGGL(gemm_lse_bf, dim3(NWG2), dim3(512), 0, stream,
                           xbf, wbf, b0, b1, tgt, partials, tgtlog);
    } else {
        hipLaunchKernelGGL(gemm_lse_f32, dim3(8000), dim3(256), 0, stream,
                           xbf, w0, b0, w1, b1, tgt, partials, tgtlog);
    }
    hipLaunchKernelGGL(lse_reduce, dim3(2 * BT / 4), dim3(256), 0, stream,
                       partials, tgtlog, logp);
    hipLaunchKernelGGL(final_loss, dim3(1), dim3(512), 0, stream, logp, tgt, pref, kl, out);
}